// Round 7
// baseline (580.316 us; speedup 1.0000x reference)
//
#include <hip/hip_runtime.h>
#include <hip/hip_cooperative_groups.h>

namespace cg = cooperative_groups;

#define BSZ 200000
#define NSTEPS 10
#define TOLFUN_C 1e-6f
#define ALPHA_C 1e-4f

// cooperative config: 256 blocks x 512 threads, SPT=2; y0 lives in LDS.
#define CNTHR 512
#define CNBLK 256
#define CNT   (CNBLK*CNTHR)   /* 131072 threads */
#define SPT   2
#define SLOTS (CNTHR*SPT)     /* 1024 per block */

// fallback config
#define FNTHR 256
#define FNBLK ((BSZ + FNTHR - 1)/FNTHR)

// ---------------- ws layout (float elements) ----------------
// State arrays used ONLY by the fallback path; coop keeps state in VGPRs/LDS.
#define OFF_Y     ((size_t)0)
#define OFF_YOLD  ((size_t)BSZ*8)
#define OFF_DY    ((size_t)BSZ*16)
#define OFF_SJ    ((size_t)BSZ*24)
#define OFF_FOLD  ((size_t)BSZ*32)
#define OFF_SLOPE ((size_t)BSZ*33)
#define OFF_RESN  ((size_t)BSZ*34)
#define OFF_F2    ((size_t)BSZ*35)
#define OFF_TFO   ((size_t)BSZ*36)
#define OFF_TRN   ((size_t)BSZ*37)
#define OFF_R     ((size_t)BSZ*38)

// Reduction slots, each on its own 256B line.
#define RSTRIDE 64            /* uint words = 256 B */
#define NSLOT   9
#define R_TOT   (2 + NSTEPS*NSLOT)
// global: slot0 = max(rn0) key, slot1 = max(ratio0) key
// per step j, base (2+j*9)*RSTRIDE:
//  +0 maxGml(maxkey) +1 anyNFdy(bit) +2 minQuad(minkey) +3 minX(minkey)
//  +4 minZ(minkey) +5 minW(minkey) +6 maxTRN(maxkey) +7 maxRatio(maxkey)
//  +8 boolmask: b0 anyArmijo, b1 anyAnot0, b2 anyDiscNeg, b3 anyBle0, b4 anyNanF
#define KEY_MAX_IDENT 0x007FFFFFu  /* fkey(-inf) */
#define KEY_MIN_IDENT 0xFF800000u  /* fkey(+inf) */

static __device__ __forceinline__ float nanmax2(float a, float b){
    return (__builtin_isnan(a) || __builtin_isnan(b)) ? __builtin_nanf("") : fmaxf(a, b);
}
static __device__ __forceinline__ float nanmin2(float a, float b){
    return (__builtin_isnan(a) || __builtin_isnan(b)) ? __builtin_nanf("") : fminf(a, b);
}
static __device__ __forceinline__ float safe_div(float n, float d){
    return (fabsf(d) > 1e-30f) ? (n / d) : 0.0f;
}
static __device__ __forceinline__ unsigned fkey(float x){
    unsigned u = __float_as_uint(x);
    return (u & 0x80000000u) ? ~u : (u | 0x80000000u);
}
static __device__ __forceinline__ float funkey(unsigned u){
    return (u & 0x80000000u) ? __uint_as_float(u & 0x7FFFFFFFu) : __uint_as_float(~u);
}
static __device__ __forceinline__ unsigned fkey_max(float x){
    if (__builtin_isnan(x)) x = __uint_as_float(0x7FC00000u);
    return fkey(x);
}
static __device__ __forceinline__ unsigned fkey_min(float x){
    if (__builtin_isnan(x)) x = __uint_as_float(0xFFC00000u);
    return fkey(x);
}
static __device__ __forceinline__ void ld8(const float* p, float* v){
    float4 a = ((const float4*)p)[0], b = ((const float4*)p)[1];
    v[0]=a.x; v[1]=a.y; v[2]=a.z; v[3]=a.w; v[4]=b.x; v[5]=b.y; v[6]=b.z; v[7]=b.w;
}
static __device__ __forceinline__ void st8(float* p, const float* v){
    float4 a, b;
    a.x=v[0]; a.y=v[1]; a.z=v[2]; a.w=v[3];
    b.x=v[4]; b.y=v[5]; b.z=v[6]; b.w=v[7];
    ((float4*)p)[0]=a; ((float4*)p)[1]=b;
}
static __device__ __forceinline__ unsigned ldslot(const unsigned* p){
    return __hip_atomic_load(p, __ATOMIC_RELAXED, __HIP_MEMORY_SCOPE_AGENT);
}
static __device__ __forceinline__ void stslot(unsigned* p, unsigned v){
    __hip_atomic_store(p, v, __ATOMIC_RELAXED, __HIP_MEMORY_SCOPE_AGENT);
}

// ---------------- shared math (pointer-based; used by BOTH paths) ----------------
// residual F = err(y) (+ tanh intermediates). Bitwise-identical at every use site.
static __device__ __forceinline__ void computeFz(
    const float* yv, const float* y0v, float dt, float c0,
    const float* sW, const float* sV, float* Fo, float* zo)
{
    float u[8];
    #pragma unroll
    for (int k=0;k<8;k++){
        float acc = 0.f;
        #pragma unroll
        for (int m=0;m<8;m++) acc += yv[m]*sW[m*8+k];
        u[k]=acc;
    }
    #pragma unroll
    for (int k=0;k<8;k++) zo[k] = tanhf(u[k]);
    #pragma unroll
    for (int i=0;i<8;i++){
        float tv = 0.f;
        #pragma unroll
        for (int k=0;k<8;k++) tv += zo[k]*sV[k*8+i];
        Fo[i] = (yv[i]-y0v[i])/dt - ((tv - 0.1f*yv[i]) + c0);
    }
}

static __device__ __forceinline__ void devInit2(const float* y0v,
    float* yold, float* dy, float* sj,
    float& fold_o, float& slope_o, float& resn_o, float& f2_o,
    float dt, float c0, const float* sW, const float* sV,
    float& rn_red, float& rat_red)
{
    #pragma unroll
    for (int i=0;i<8;i++){ yold[i]=y0v[i]; dy[i]=0.f; }
    float Fv[8], z[8];
    computeFz(y0v, y0v, dt, c0, sW, sV, Fv, z);
    #pragma unroll
    for (int k=0;k<8;k++) sj[k] = 1.0f - z[k]*z[k];
    float fold = 0.f;
    #pragma unroll
    for (int i=0;i<8;i++) fold += Fv[i]*Fv[i];
    float rn0 = fabsf(Fv[0]);
    #pragma unroll
    for (int i=1;i<8;i++) rn0 = nanmax2(rn0, fabsf(Fv[i]));
    fold_o=fold; slope_o=0.f; resn_o=rn0; f2_o=fold;
    rn_red  = nanmax2(rn_red, rn0);
    rat_red = nanmax2(rat_red, safe_div(rn0, 100.0f*rn0));
}

// Newton direction from current point y_cur; rebases yold:=y_cur, writes dy/sj/fold/slope.
static __device__ __forceinline__ void devA2(const float* y_cur, const float* y0v,
    float* yold, float* dy, float* sj, float& fold_o, float& slope_o,
    float dt, float invdt, float c0, const float* sW, const float* sV,
    bool recompute, float& gml, bool& nf)
{
    float Fv[8], z[8];
    computeFz(y_cur, y0v, dt, c0, sW, sV, Fv, z);
    if (recompute){
        #pragma unroll
        for (int k=0;k<8;k++) sj[k] = 1.0f - z[k]*z[k];
    }
    float J[8][8];
    #pragma unroll
    for (int j=0;j<8;j++){
        float zj[8];
        #pragma unroll
        for (int k=0;k<8;k++) zj[k] = sW[j*8+k]*sj[k];
        #pragma unroll
        for (int i=0;i<8;i++){
            float acc = 0.f;
            #pragma unroll
            for (int k=0;k<8;k++) acc += zj[k]*sV[k*8+i];
            J[i][j] = (i==j) ? (invdt - (acc - 0.1f)) : (0.0f - acc);
        }
    }
    float fold = 0.f;
    #pragma unroll
    for (int i=0;i<8;i++) fold += Fv[i]*Fv[i];
    float gv[8];
    #pragma unroll
    for (int j=0;j<8;j++){
        float acc = 0.f;
        #pragma unroll
        for (int i=0;i<8;i++) acc += Fv[i]*J[i][j];
        gv[j]=acc;
    }
    float x[8];
    #pragma unroll
    for (int i=0;i<8;i++) x[i]=Fv[i];
    #pragma unroll
    for (int c=0;c<8;c++){
        float ip = 1.0f / J[c][c];
        #pragma unroll
        for (int r2=c+1;r2<8;r2++){
            float m = J[r2][c]*ip;
            #pragma unroll
            for (int jj=c+1;jj<8;jj++) J[r2][jj] -= m*J[c][jj];
            x[r2] -= m*x[c];
        }
    }
    float wv[8];
    #pragma unroll
    for (int c=7;c>=0;c--){
        float acc = x[c];
        #pragma unroll
        for (int jj=c+1;jj<8;jj++) acc -= J[c][jj]*wv[jj];
        wv[c] = acc / J[c][c];
    }
    #pragma unroll
    for (int i=0;i<8;i++){
        yold[i] = y_cur[i];      // eager rebase (safe: freeze/idempotence analysis)
        dy[i]   = -wv[i];
    }
    float slope = 0.f;
    #pragma unroll
    for (int j=0;j<8;j++) slope += gv[j]*dy[j];
    fold_o = fold; slope_o = slope;
    #pragma unroll
    for (int i=0;i<8;i++){
        float rr = fabsf(dy[i]) / nanmax2(fabsf(y_cur[i]), 1.0f);
        gml = nanmax2(gml, rr);
        nf = nf || !__builtin_isfinite(dy[i]);
    }
}

static __device__ __forceinline__ void devB2(const float* yold, const float* dy,
    const float* y0v, float foldv, float slopev, float resnv, float f2v,
    float dt, float c0, const float* sW, const float* sV, float lam, float lam2v,
    float& tfo_o, float& trn_o,
    bool& armijo, float& lq, bool& aNot0, bool& dN, bool& ble,
    float& mX, float& mZ, float& mW, bool& nanf, float& trnR, float& ratR)
{
    float yn[8];
    #pragma unroll
    for (int i=0;i<8;i++) yn[i] = yold[i] + dy[i]*lam;
    float Ft[8], z[8];
    computeFz(yn, y0v, dt, c0, sW, sV, Ft, z);
    float f_obj = 0.f;
    #pragma unroll
    for (int i=0;i<8;i++) f_obj += Ft[i]*Ft[i];
    float rn = fabsf(Ft[0]);
    #pragma unroll
    for (int i=1;i<8;i++) rn = nanmax2(rn, fabsf(Ft[i]));
    tfo_o = f_obj; trn_o = rn;    // pending commit scalars
    armijo = armijo || (f_obj > (foldv + (ALPHA_C*lam)*slopev));
    lq = nanmin2(lq, safe_div((-slopev)*0.5f, (f_obj - foldv) - slopev));
    float lam1v = lam;
    float Af = safe_div(1.0f, lam1v - lam2v);
    float i1 = safe_div(1.0f, lam1v*lam1v);
    float i2 = safe_div(1.0f, lam2v*lam2v);
    float Cc0 = (f_obj - foldv) - lam1v*slopev;
    float Cc1 = (f2v   - foldv) - lam2v*slopev;
    float av = Af*(i1*Cc0 - i2*Cc1);
    float bv = Af*((-(lam2v*i1))*Cc0 + (lam1v*i2)*Cc1);
    float disc = bv*bv - (3.0f*av)*slopev;
    float dm = __builtin_isnan(disc) ? disc : fmaxf(disc, 0.0f);
    float sq = sqrtf(dm);
    aNot0 = aNot0 || (av != 0.0f);
    dN    = dN    || (disc < 0.0f);
    ble   = ble   || (bv <= 0.0f);
    mX = nanmin2(mX, safe_div(-slopev, 2.0f*bv));
    mZ = nanmin2(mZ, safe_div(-bv + sq, 3.0f*av));
    mW = nanmin2(mW, safe_div(-slopev, bv + sq));
    nanf = nanf || !__builtin_isfinite(f_obj);
    trnR = nanmax2(trnR, rn);
    ratR = nanmax2(ratR, safe_div(rn, resnv));
}

// ---------------- scalar control chain ----------------
struct ScalarState {
    float lam, lam1, lam2, lam_min, maxrn, ratmax;
    int   niter, exitflag;
    bool  upd_prev, cont_prev;
};

static __device__ void advance(ScalarState& s, const unsigned* R, int j){
    const unsigned* r = R + (size_t)(2 + j*NSLOT)*RSTRIDE;
    unsigned v0 = ldslot(r + (size_t)0*RSTRIDE);
    unsigned v1 = ldslot(r + (size_t)1*RSTRIDE);
    unsigned v2 = ldslot(r + (size_t)2*RSTRIDE);
    unsigned v3 = ldslot(r + (size_t)3*RSTRIDE);
    unsigned v4 = ldslot(r + (size_t)4*RSTRIDE);
    unsigned v5 = ldslot(r + (size_t)5*RSTRIDE);
    unsigned v6 = ldslot(r + (size_t)6*RSTRIDE);
    unsigned v7 = ldslot(r + (size_t)7*RSTRIDE);
    unsigned v8 = ldslot(r + (size_t)8*RSTRIDE);
    bool active    = ((s.maxrn > TOLFUN_C) || (s.lam < 1.0f)) && (s.exitflag >= 0) && (s.niter <= 1000);
    bool is_newton = (s.lam == 1.0f);
    float lam_min_new = is_newton ? safe_div(1e-12f, funkey(v0)) : s.lam_min;
    bool brk = (s.lam < lam_min_new);
    bool bad = is_newton ? (v1 != 0u) : false;
    bool upd = active && !brk && !bad;
    int niter_new = active ? (is_newton ? s.niter + 1 : s.niter) : s.niter;
    int ef_new = s.exitflag;
    if (active && brk) ef_new = 2;
    else if (active && !brk && bad) ef_new = -1;
    bool cont = false;
    if (upd){
        float lam1c = s.lam;
        unsigned bm = v8;
        bool backtrack = (bm & 1u) != 0u;
        float lamq  = funkey(v2);
        bool allA0  = (bm & 2u) == 0u;
        bool anyDN  = (bm & 4u) != 0u;
        bool anyB0  = (bm & 8u) != 0u;
        float lam_tmp_min = allA0 ? funkey(v3)
                          : (anyDN ? (0.5f*lam1c)
                          : (anyB0 ? funkey(v4) : funkey(v5)));
        float lam_cubic = nanmin2(lam_tmp_min, 0.5f*lam1c);
        float lam_bt = (s.lam == 1.0f) ? lamq : lam_cubic;
        bool nanf = (bm & 16u) != 0u;
        float lam_new = backtrack ? lam_bt : (nanf ? 0.5f*lam1c : 1.0f);
        cont = (lam_new < 1.0f);
        float lam2_new = cont ? lam1c : s.lam2;
        if (cont) lam_new = nanmax2(lam_new, 0.1f*lam1c);
        float maxrn_new  = cont ? s.maxrn  : funkey(v6);
        float ratmax_new = cont ? s.ratmax : funkey(v7);
        s.lam = lam_new; s.lam1 = lam1c; s.lam2 = lam2_new;
        s.lam_min = lam_min_new; s.maxrn = maxrn_new; s.ratmax = ratmax_new;
    }
    s.niter = niter_new; s.exitflag = ef_new;
    s.upd_prev = upd; s.cont_prev = cont;
}

static __device__ ScalarState replayN(const unsigned* R, int n){
    ScalarState s;
    s.lam=1.0f; s.lam1=1.0f; s.lam2=0.5f; s.lam_min=0.0f;
    s.maxrn  = funkey(ldslot(&R[0]));
    s.ratmax = funkey(ldslot(&R[(size_t)1*RSTRIDE]));
    s.niter=0; s.exitflag=1; s.upd_prev=false; s.cont_prev=false;
    for (int j=0;j<n;++j) advance(s, R, j);
    return s;
}

// ================= cooperative fused kernel =================
// y is NOT stored per-sample: every commit uses the wave-uniform lam1, so
// y == yold + dy*lamc where lamc is a uniform scalar tracked alongside S.
// y0 lives in LDS (element-major, conflict-free) to cut persistent VGPRs.
__global__ __launch_bounds__(CNTHR, 1) void kFused(
    const float* __restrict__ y0g, const float* __restrict__ Wm, const float* __restrict__ Vm,
    const float* __restrict__ dtp, const float* __restrict__ tp,
    float* __restrict__ ws, float* __restrict__ out)
{
    cg::grid_group gridg = cg::this_grid();
    __shared__ float sW[64], sV[64];
    __shared__ float sY0[8*SLOTS];      // 32 KB: y0 element-major
    __shared__ float redF[6][8];
    __shared__ unsigned redB[8];
    int t = threadIdx.x;
    if (t < 64) sW[t] = Wm[t];
    else if (t < 128) sV[t-64] = Vm[t-64];
    unsigned* R = (unsigned*)(ws + OFF_R);
    if (blockIdx.x == 0 && t < R_TOT){
        unsigned v;
        if (t < 2) v = KEY_MAX_IDENT;
        else {
            int off = (t - 2) % NSLOT;
            bool ismin = (off==2 || off==3 || off==4 || off==5);
            bool ismax = (off==0 || off==6 || off==7);
            v = ismin ? KEY_MIN_IDENT : (ismax ? KEY_MAX_IDENT : 0u);
        }
        stslot(&R[(size_t)t*RSTRIDE], v);
    }
    __syncthreads();
    gridg.sync();

    int gtid = blockIdx.x*CNTHR + t;
    float dt = *dtp, invdt = 1.0f/dt, c0 = 0.01f*sinf(*tp);

    // per-sample persistent register state (30 floats/sample)
    bool  valid[SPT];
    float yold[SPT][8], dyv[SPT][8], sjv[SPT][8];
    float foldv[SPT], slopev[SPT], resnv[SPT], f2v[SPT], tfov[SPT], trnv[SPT];
    float lamc = 0.0f;   // uniform: y = yold + dy*lamc

    float rn_red = -__builtin_inff(), rat_red = -__builtin_inff();
    #pragma unroll
    for (int q=0;q<SPT;q++){
        int sid = gtid + q*CNT;
        int slot = q*CNTHR + t;
        valid[q] = sid < BSZ;
        if (valid[q]){
            float y0v[8];
            ld8(y0g + (size_t)sid*8, y0v);
            #pragma unroll
            for (int i=0;i<8;i++) sY0[i*SLOTS + slot] = y0v[i];
            devInit2(y0v, yold[q], dyv[q], sjv[q],
                     foldv[q], slopev[q], resnv[q], f2v[q],
                     dt, c0, sW, sV, rn_red, rat_red);
            tfov[q]=0.f; trnv[q]=0.f;
        } else {
            #pragma unroll
            for (int i=0;i<8;i++){ sY0[i*SLOTS + slot]=0; yold[q][i]=0; dyv[q][i]=0; sjv[q][i]=0; }
            foldv[q]=0; slopev[q]=0; resnv[q]=0; f2v[q]=0; tfov[q]=0; trnv[q]=0;
        }
    }
    #pragma unroll
    for (int o=32;o>=1;o>>=1){
        rn_red  = nanmax2(rn_red,  __shfl_xor(rn_red,  o, 64));
        rat_red = nanmax2(rat_red, __shfl_xor(rat_red, o, 64));
    }
    {
        int w = t >> 6;
        if ((t & 63) == 0){ redF[0][w] = rn_red; redF[1][w] = rat_red; }
        __syncthreads();
        if (t == 0){
            float a = redF[0][0];
            #pragma unroll
            for (int w2=1;w2<8;w2++) a = nanmax2(a, redF[0][w2]);
            atomicMax(&R[0], fkey_max(a));
        } else if (t == 1){
            float b = redF[1][0];
            #pragma unroll
            for (int w2=1;w2<8;w2++) b = nanmax2(b, redF[1][w2]);
            atomicMax(&R[(size_t)1*RSTRIDE], fkey_max(b));
        }
    }
    gridg.sync();

    ScalarState S;
    S.lam=1.0f; S.lam1=1.0f; S.lam2=0.5f; S.lam_min=0.0f;
    S.maxrn  = funkey(ldslot(&R[0]));
    S.ratmax = funkey(ldslot(&R[(size_t)1*RSTRIDE]));
    S.niter=0; S.exitflag=1; S.upd_prev=false; S.cont_prev=false;

    #pragma unroll 1
    for (int k=1; k<=NSTEPS; ++k){
        // ---- commit pending trial from step k-1 (gate now known) ----
        if (S.upd_prev){
            lamc = S.lam1;
            #pragma unroll
            for (int q=0;q<SPT;q++){
                if (!valid[q]) continue;
                if (S.cont_prev) f2v[q]  = tfov[q];
                else             resnv[q] = trnv[q];
            }
        }
        bool active    = ((S.maxrn > TOLFUN_C) || (S.lam < 1.0f)) && (S.exitflag >= 0) && (S.niter <= 1000);
        bool is_newton = (S.lam == 1.0f);
        unsigned* r = R + (size_t)(2 + (k-1)*NSLOT)*RSTRIDE;

        if (active && is_newton){
            bool recompute = (S.ratmax > 0.2f);
            float gml = -__builtin_inff(); bool nf = false;
            #pragma unroll
            for (int q=0;q<SPT;q++){
                if (!valid[q]) continue;
                int slot = q*CNTHR + t;
                float y_cur[8], y0v[8];
                #pragma unroll
                for (int i=0;i<8;i++){
                    y_cur[i] = yold[q][i] + dyv[q][i]*lamc;
                    y0v[i]   = sY0[i*SLOTS + slot];
                }
                devA2(y_cur, y0v, yold[q], dyv[q], sjv[q], foldv[q], slopev[q],
                      dt, invdt, c0, sW, sV, recompute, gml, nf);
            }
            lamc = 0.0f;   // yold rebased to current y
            #pragma unroll
            for (int o=32;o>=1;o>>=1) gml = nanmax2(gml, __shfl_xor(gml, o, 64));
            unsigned long long anym = __ballot(nf ? 1 : 0);
            int w = t >> 6;
            if ((t & 63) == 0){ redF[0][w] = gml; redB[w] = anym ? 1u : 0u; }
            __syncthreads();
            if (t == 0){
                float v = redF[0][0];
                #pragma unroll
                for (int w2=1;w2<8;w2++) v = nanmax2(v, redF[0][w2]);
                atomicMax(&r[0], fkey_max(v));
            } else if (t == 1){
                unsigned bm = 0u;
                #pragma unroll
                for (int w2=0;w2<8;w2++) bm |= redB[w2];
                if (bm) atomicOr(&r[(size_t)1*RSTRIDE], 1u);
            }
            __syncthreads();  // protect redF/redB reuse by phase B
        }

        if (active){
            float lam = S.lam, lam2v = S.lam2;
            bool armijo=false, aNot0=false, dN=false, ble=false, nanf=false;
            float lq=__builtin_inff(), mX=__builtin_inff(), mZ=__builtin_inff(), mW=__builtin_inff();
            float trnR=-__builtin_inff(), ratR=-__builtin_inff();
            #pragma unroll
            for (int q=0;q<SPT;q++){
                if (!valid[q]) continue;
                int slot = q*CNTHR + t;
                float y0v[8];
                #pragma unroll
                for (int i=0;i<8;i++) y0v[i] = sY0[i*SLOTS + slot];
                devB2(yold[q], dyv[q], y0v, foldv[q], slopev[q], resnv[q], f2v[q],
                      dt, c0, sW, sV, lam, lam2v, tfov[q], trnv[q],
                      armijo, lq, aNot0, dN, ble, mX, mZ, mW, nanf, trnR, ratR);
            }
            #pragma unroll
            for (int o=32;o>=1;o>>=1){
                lq   = nanmin2(lq,   __shfl_xor(lq,   o, 64));
                mX   = nanmin2(mX,   __shfl_xor(mX,   o, 64));
                mZ   = nanmin2(mZ,   __shfl_xor(mZ,   o, 64));
                mW   = nanmin2(mW,   __shfl_xor(mW,   o, 64));
                trnR = nanmax2(trnR, __shfl_xor(trnR, o, 64));
                ratR = nanmax2(ratR, __shfl_xor(ratR, o, 64));
            }
            unsigned long long bArm = __ballot(armijo ? 1 : 0);
            unsigned long long bA0  = __ballot(aNot0  ? 1 : 0);
            unsigned long long bDN  = __ballot(dN     ? 1 : 0);
            unsigned long long bB0  = __ballot(ble    ? 1 : 0);
            unsigned long long bNF  = __ballot(nanf   ? 1 : 0);
            int w = t >> 6;
            if ((t & 63) == 0){
                redF[0][w]=lq; redF[1][w]=mX; redF[2][w]=mZ; redF[3][w]=mW;
                redF[4][w]=trnR; redF[5][w]=ratR;
                redB[w] = (bArm?1u:0u) | (bA0?2u:0u) | (bDN?4u:0u) | (bB0?8u:0u) | (bNF?16u:0u);
            }
            __syncthreads();
            if (t < 6){
                float v = redF[t][0];
                bool ismin = (t < 4);
                #pragma unroll
                for (int w2=1;w2<8;w2++) v = ismin ? nanmin2(v, redF[t][w2]) : nanmax2(v, redF[t][w2]);
                unsigned* p = &r[(size_t)(t + 2)*RSTRIDE];
                if (ismin) atomicMin(p, fkey_min(v));
                else       atomicMax(p, fkey_max(v));
            } else if (t == 6){
                unsigned bm = 0u;
                #pragma unroll
                for (int w2=0;w2<8;w2++) bm |= redB[w2];
                if (bm) atomicOr(&r[(size_t)8*RSTRIDE], bm);
            }
        }

        gridg.sync();           // also block-syncs: protects redF reuse next iter
        advance(S, R, k-1);
    }

    if (S.upd_prev) lamc = S.lam1;   // final commit (y only; f2/resn not output)
    #pragma unroll
    for (int q=0;q<SPT;q++){
        if (!valid[q]) continue;
        int sid = gtid + q*CNT;
        int slot = q*CNTHR + t;
        float yf[8], y0v[8];
        #pragma unroll
        for (int i=0;i<8;i++){
            yf[i]  = yold[q][i] + dyv[q][i]*lamc;
            y0v[i] = sY0[i*SLOTS + slot];
        }
        st8(out + (size_t)sid*8, yf);
        float Fv[8], z[8];
        computeFz(yf, y0v, dt, c0, sW, sV, Fv, z);
        st8(out + (size_t)BSZ*8 + (size_t)sid*8, Fv);
    }
    if (gtid == 0) out[(size_t)BSZ*16] = (float)S.exitflag;
}

// ================= fallback path (same math, ws-resident state) =================
__global__ void kPre(unsigned* __restrict__ R){
    int i = threadIdx.x;
    if (i >= R_TOT) return;
    unsigned v;
    if (i < 2) v = KEY_MAX_IDENT;
    else {
        int off = (i - 2) % NSLOT;
        bool ismin = (off==2 || off==3 || off==4 || off==5);
        bool ismax = (off==0 || off==6 || off==7);
        v = ismin ? KEY_MIN_IDENT : (ismax ? KEY_MAX_IDENT : 0u);
    }
    R[(size_t)i*RSTRIDE] = v;
}

__global__ __launch_bounds__(FNTHR) void fInit(
    const float* __restrict__ y0g, const float* __restrict__ Wm, const float* __restrict__ Vm,
    const float* __restrict__ dtp, const float* __restrict__ tp, float* __restrict__ ws)
{
    __shared__ float sW[64], sV[64];
    __shared__ float red[2][4];
    int t = threadIdx.x;
    if (t < 64) sW[t] = Wm[t];
    else if (t < 128) sV[t-64] = Vm[t-64];
    __syncthreads();
    unsigned* R = (unsigned*)(ws + OFF_R);
    int tid = blockIdx.x*FNTHR + t;
    bool valid = tid < BSZ;
    float dt = *dtp, c0 = 0.01f*sinf(*tp);
    float rn_red = -__builtin_inff(), rat_red = -__builtin_inff();
    if (valid){
        float y0v[8], yo[8], dv[8], sj[8], fold, slope, resn, f2;
        ld8(y0g + (size_t)tid*8, y0v);
        devInit2(y0v, yo, dv, sj, fold, slope, resn, f2, dt, c0, sW, sV, rn_red, rat_red);
        st8(ws+OFF_Y   +(size_t)tid*8, y0v);
        st8(ws+OFF_YOLD+(size_t)tid*8, yo);
        st8(ws+OFF_DY  +(size_t)tid*8, dv);
        st8(ws+OFF_SJ  +(size_t)tid*8, sj);
        ws[OFF_FOLD+tid]=fold; ws[OFF_SLOPE+tid]=slope;
        ws[OFF_RESN+tid]=resn; ws[OFF_F2+tid]=f2;
        ws[OFF_TFO+tid]=0.f;   ws[OFF_TRN+tid]=0.f;
    }
    #pragma unroll
    for (int o=32;o>=1;o>>=1){
        rn_red  = nanmax2(rn_red,  __shfl_xor(rn_red,  o, 64));
        rat_red = nanmax2(rat_red, __shfl_xor(rat_red, o, 64));
    }
    int w = t >> 6;
    if ((t & 63) == 0){ red[0][w]=rn_red; red[1][w]=rat_red; }
    __syncthreads();
    if (t == 0){
        float a = red[0][0];
        for (int w2=1;w2<4;w2++) a = nanmax2(a, red[0][w2]);
        atomicMax(&R[0], fkey_max(a));
    } else if (t == 1){
        float b = red[1][0];
        for (int w2=1;w2<4;w2++) b = nanmax2(b, red[1][w2]);
        atomicMax(&R[(size_t)1*RSTRIDE], fkey_max(b));
    }
}

__global__ __launch_bounds__(FNTHR) void fStep(
    const float* __restrict__ y0g, const float* __restrict__ Wm, const float* __restrict__ Vm,
    const float* __restrict__ dtp, const float* __restrict__ tp,
    float* __restrict__ ws, int step)
{
    __shared__ float sW[64], sV[64];
    __shared__ float redF[6][4];
    __shared__ unsigned redB[4];
    int t = threadIdx.x;
    if (t < 64) sW[t] = Wm[t];
    else if (t < 128) sV[t-64] = Vm[t-64];
    __syncthreads();
    unsigned* R = (unsigned*)(ws + OFF_R);
    ScalarState S = replayN(R, step-1);
    bool active    = ((S.maxrn > TOLFUN_C) || (S.lam < 1.0f)) && (S.exitflag >= 0) && (S.niter <= 1000);
    bool is_newton = (S.lam == 1.0f);
    if (!S.upd_prev && !active) return;   // uniform

    int tid = blockIdx.x*FNTHR + t;
    bool valid = tid < BSZ;
    float dt = *dtp, invdt = 1.0f/dt, c0 = 0.01f*sinf(*tp);
    unsigned* r = R + (size_t)(2 + (step-1)*NSLOT)*RSTRIDE;

    float y0v[8], yv[8], yo[8], dv[8], sj[8], fold=0, slope=0, resn=0, f2=0;
    if (valid){
        ld8(y0g + (size_t)tid*8, y0v);
        ld8(ws+OFF_Y   +(size_t)tid*8, yv);
        ld8(ws+OFF_YOLD+(size_t)tid*8, yo);
        ld8(ws+OFF_DY  +(size_t)tid*8, dv);
        ld8(ws+OFF_SJ  +(size_t)tid*8, sj);
        fold=ws[OFF_FOLD+tid]; slope=ws[OFF_SLOPE+tid];
        resn=ws[OFF_RESN+tid]; f2=ws[OFF_F2+tid];
        if (S.upd_prev){
            #pragma unroll
            for (int i=0;i<8;i++) yv[i] = yo[i] + dv[i]*S.lam1;
            st8(ws+OFF_Y+(size_t)tid*8, yv);
            if (S.cont_prev){ f2 = ws[OFF_TFO+tid];  ws[OFF_F2+tid]   = f2; }
            else            { resn = ws[OFF_TRN+tid]; ws[OFF_RESN+tid] = resn; }
        }
    }
    if (!active) return;  // uniform

    if (is_newton){
        bool recompute = (S.ratmax > 0.2f);
        float gml = -__builtin_inff(); bool nf = false;
        if (valid){
            devA2(yv, y0v, yo, dv, sj, fold, slope, dt, invdt, c0, sW, sV, recompute, gml, nf);
            st8(ws+OFF_YOLD+(size_t)tid*8, yo);
            st8(ws+OFF_DY  +(size_t)tid*8, dv);
            if (recompute) st8(ws+OFF_SJ+(size_t)tid*8, sj);
            ws[OFF_FOLD+tid]  = fold;
            ws[OFF_SLOPE+tid] = slope;
        }
        #pragma unroll
        for (int o=32;o>=1;o>>=1) gml = nanmax2(gml, __shfl_xor(gml, o, 64));
        unsigned long long anym = __ballot(nf ? 1 : 0);
        int w = t >> 6;
        if ((t & 63) == 0){ redF[0][w] = gml; redB[w] = anym ? 1u : 0u; }
        __syncthreads();
        if (t == 0){
            float v = redF[0][0];
            for (int w2=1;w2<4;w2++) v = nanmax2(v, redF[0][w2]);
            atomicMax(&r[0], fkey_max(v));
        } else if (t == 1){
            unsigned bm = redB[0]|redB[1]|redB[2]|redB[3];
            if (bm) atomicOr(&r[(size_t)1*RSTRIDE], 1u);
        }
        __syncthreads();
    }

    {
        float lam = S.lam, lam2v = S.lam2;
        bool armijo=false, aNot0=false, dN=false, ble=false, nanf=false;
        float lq=__builtin_inff(), mX=__builtin_inff(), mZ=__builtin_inff(), mW=__builtin_inff();
        float trnR=-__builtin_inff(), ratR=-__builtin_inff();
        if (valid){
            float tfo, trn;
            devB2(yo, dv, y0v, fold, slope, resn, f2, dt, c0, sW, sV, lam, lam2v,
                  tfo, trn, armijo, lq, aNot0, dN, ble, mX, mZ, mW, nanf, trnR, ratR);
            ws[OFF_TFO+tid] = tfo;
            ws[OFF_TRN+tid] = trn;
        }
        #pragma unroll
        for (int o=32;o>=1;o>>=1){
            lq   = nanmin2(lq,   __shfl_xor(lq,   o, 64));
            mX   = nanmin2(mX,   __shfl_xor(mX,   o, 64));
            mZ   = nanmin2(mZ,   __shfl_xor(mZ,   o, 64));
            mW   = nanmin2(mW,   __shfl_xor(mW,   o, 64));
            trnR = nanmax2(trnR, __shfl_xor(trnR, o, 64));
            ratR = nanmax2(ratR, __shfl_xor(ratR, o, 64));
        }
        unsigned long long bArm = __ballot(armijo ? 1 : 0);
        unsigned long long bA0  = __ballot(aNot0  ? 1 : 0);
        unsigned long long bDN  = __ballot(dN     ? 1 : 0);
        unsigned long long bB0  = __ballot(ble    ? 1 : 0);
        unsigned long long bNF  = __ballot(nanf   ? 1 : 0);
        int w = t >> 6;
        if ((t & 63) == 0){
            redF[0][w]=lq; redF[1][w]=mX; redF[2][w]=mZ; redF[3][w]=mW;
            redF[4][w]=trnR; redF[5][w]=ratR;
            redB[w] = (bArm?1u:0u) | (bA0?2u:0u) | (bDN?4u:0u) | (bB0?8u:0u) | (bNF?16u:0u);
        }
        __syncthreads();
        if (t < 6){
            float v = redF[t][0];
            bool ismin = (t < 4);
            for (int w2=1;w2<4;w2++) v = ismin ? nanmin2(v, redF[t][w2]) : nanmax2(v, redF[t][w2]);
            unsigned* p = &r[(size_t)(t + 2)*RSTRIDE];
            if (ismin) atomicMin(p, fkey_min(v));
            else       atomicMax(p, fkey_max(v));
        } else if (t == 6){
            unsigned bm = redB[0]|redB[1]|redB[2]|redB[3];
            if (bm) atomicOr(&r[(size_t)8*RSTRIDE], bm);
        }
    }
}

__global__ __launch_bounds__(FNTHR) void fOut(
    const float* __restrict__ y0g, const float* __restrict__ Wm, const float* __restrict__ Vm,
    const float* __restrict__ dtp, const float* __restrict__ tp,
    const float* __restrict__ ws, float* __restrict__ out)
{
    __shared__ float sW[64], sV[64];
    int t = threadIdx.x;
    if (t < 64) sW[t] = Wm[t];
    else if (t < 128) sV[t-64] = Vm[t-64];
    __syncthreads();
    const unsigned* R = (const unsigned*)(ws + OFF_R);
    ScalarState S = replayN(R, NSTEPS);
    int tid = blockIdx.x*FNTHR + t;
    float dt = *dtp, c0 = 0.01f*sinf(*tp);
    if (tid < BSZ){
        float y0v[8], yv[8];
        ld8(y0g + (size_t)tid*8, y0v);
        ld8(ws+OFF_Y+(size_t)tid*8, yv);
        if (S.upd_prev){
            float yo[8], dv[8];
            ld8(ws+OFF_YOLD+(size_t)tid*8, yo);
            ld8(ws+OFF_DY  +(size_t)tid*8, dv);
            #pragma unroll
            for (int i=0;i<8;i++) yv[i] = yo[i] + dv[i]*S.lam1;
        }
        st8(out + (size_t)tid*8, yv);
        float Fv[8], z[8];
        computeFz(yv, y0v, dt, c0, sW, sV, Fv, z);
        st8(out + (size_t)BSZ*8 + (size_t)tid*8, Fv);
    }
    if (blockIdx.x == 0 && t == 0) out[(size_t)BSZ*16] = (float)S.exitflag;
}

extern "C" void kernel_launch(void* const* d_in, const int* in_sizes, int n_in,
                              void* d_out, int out_size, void* d_ws, size_t ws_size,
                              hipStream_t stream)
{
    const float* y0g = (const float*)d_in[0];
    const float* dtp = (const float*)d_in[1];
    const float* tp  = (const float*)d_in[2];
    const float* Wm  = (const float*)d_in[3];
    const float* Vm  = (const float*)d_in[4];
    float* ws   = (float*)d_ws;
    float* outp = (float*)d_out;

    void* args[] = {(void*)&y0g, (void*)&Wm, (void*)&Vm, (void*)&dtp, (void*)&tp,
                    (void*)&ws, (void*)&outp};
    hipError_t rc = hipLaunchCooperativeKernel((const void*)kFused, dim3(CNBLK), dim3(CNTHR),
                                               args, 0, stream);
    if (rc != hipSuccess){
        // deterministic fallback: same math, ws-resident state, 13 launches
        hipLaunchKernelGGL(kPre, dim3(1), dim3(128), 0, stream, (unsigned*)(ws + OFF_R));
        hipLaunchKernelGGL(fInit, dim3(FNBLK), dim3(FNTHR), 0, stream, y0g, Wm, Vm, dtp, tp, ws);
        for (int s = 1; s <= NSTEPS; ++s)
            hipLaunchKernelGGL(fStep, dim3(FNBLK), dim3(FNTHR), 0, stream, y0g, Wm, Vm, dtp, tp, ws, s);
        hipLaunchKernelGGL(fOut, dim3(FNBLK), dim3(FNTHR), 0, stream, y0g, Wm, Vm, dtp, tp, ws, outp);
    }
}

// Round 9
// 446.868 us; speedup vs baseline: 1.2986x; 1.2986x over previous
//
#include <hip/hip_runtime.h>
#include <hip/hip_cooperative_groups.h>

namespace cg = cooperative_groups;

#define BSZ 200000
#define NSTEPS 10
#define TOLFUN_C 1e-6f
#define ALPHA_C 1e-4f

// cooperative config: 256 blocks x 256 threads (proven launch config, rounds
// 5-7), SPT=4. Persistent regs: 22 floats/sample (yold,dy + 6 scalars);
// sj in LDS; y0 re-read from global (L2-resident) at each use.
#define CNTHR 256
#define CNBLK 256
#define CNT   (CNBLK*CNTHR)   /* 65536 threads */
#define SPT   4
#define SLOTS (CNTHR*SPT)     /* 1024 per block */

// fallback config
#define FNTHR 256
#define FNBLK ((BSZ + FNTHR - 1)/FNTHR)

// ---------------- ws layout (float elements) ----------------
// State arrays used ONLY by the fallback path.
#define OFF_Y     ((size_t)0)
#define OFF_YOLD  ((size_t)BSZ*8)
#define OFF_DY    ((size_t)BSZ*16)
#define OFF_SJ    ((size_t)BSZ*24)
#define OFF_FOLD  ((size_t)BSZ*32)
#define OFF_SLOPE ((size_t)BSZ*33)
#define OFF_RESN  ((size_t)BSZ*34)
#define OFF_F2    ((size_t)BSZ*35)
#define OFF_TFO   ((size_t)BSZ*36)
#define OFF_TRN   ((size_t)BSZ*37)
#define OFF_R     ((size_t)BSZ*38)

// Reduction slots, each on its own 256B line.
#define RSTRIDE 64            /* uint words = 256 B */
#define NSLOT   9
#define R_TOT   (2 + NSTEPS*NSLOT)
// global: slot0 = max(rn0) key, slot1 = max(ratio0) key
// per step j, base (2+j*9)*RSTRIDE:
//  +0 maxGml(maxkey) +1 anyNFdy(bit) +2 minQuad(minkey) +3 minX(minkey)
//  +4 minZ(minkey) +5 minW(minkey) +6 maxTRN(maxkey) +7 maxRatio(maxkey)
//  +8 boolmask: b0 anyArmijo, b1 anyAnot0, b2 anyDiscNeg, b3 anyBle0, b4 anyNanF
#define KEY_MAX_IDENT 0x007FFFFFu  /* fkey(-inf) */
#define KEY_MIN_IDENT 0xFF800000u  /* fkey(+inf) */

static __device__ __forceinline__ float nanmax2(float a, float b){
    return (__builtin_isnan(a) || __builtin_isnan(b)) ? __builtin_nanf("") : fmaxf(a, b);
}
static __device__ __forceinline__ float nanmin2(float a, float b){
    return (__builtin_isnan(a) || __builtin_isnan(b)) ? __builtin_nanf("") : fminf(a, b);
}
static __device__ __forceinline__ float safe_div(float n, float d){
    return (fabsf(d) > 1e-30f) ? (n / d) : 0.0f;
}
static __device__ __forceinline__ unsigned fkey(float x){
    unsigned u = __float_as_uint(x);
    return (u & 0x80000000u) ? ~u : (u | 0x80000000u);
}
static __device__ __forceinline__ float funkey(unsigned u){
    return (u & 0x80000000u) ? __uint_as_float(u & 0x7FFFFFFFu) : __uint_as_float(~u);
}
static __device__ __forceinline__ unsigned fkey_max(float x){
    if (__builtin_isnan(x)) x = __uint_as_float(0x7FC00000u);
    return fkey(x);
}
static __device__ __forceinline__ unsigned fkey_min(float x){
    if (__builtin_isnan(x)) x = __uint_as_float(0xFFC00000u);
    return fkey(x);
}
static __device__ __forceinline__ void ld8(const float* p, float* v){
    float4 a = ((const float4*)p)[0], b = ((const float4*)p)[1];
    v[0]=a.x; v[1]=a.y; v[2]=a.z; v[3]=a.w; v[4]=b.x; v[5]=b.y; v[6]=b.z; v[7]=b.w;
}
static __device__ __forceinline__ void st8(float* p, const float* v){
    float4 a, b;
    a.x=v[0]; a.y=v[1]; a.z=v[2]; a.w=v[3];
    b.x=v[4]; b.y=v[5]; b.z=v[6]; b.w=v[7];
    ((float4*)p)[0]=a; ((float4*)p)[1]=b;
}
static __device__ __forceinline__ unsigned ldslot(const unsigned* p){
    return __hip_atomic_load(p, __ATOMIC_RELAXED, __HIP_MEMORY_SCOPE_AGENT);
}
static __device__ __forceinline__ void stslot(unsigned* p, unsigned v){
    __hip_atomic_store(p, v, __ATOMIC_RELAXED, __HIP_MEMORY_SCOPE_AGENT);
}

// ---------------- shared math (pointer-based; used by BOTH paths) ----------------
static __device__ __forceinline__ void computeFz(
    const float* yv, const float* y0v, float dt, float c0,
    const float* sW, const float* sV, float* Fo, float* zo)
{
    float u[8];
    #pragma unroll
    for (int k=0;k<8;k++){
        float acc = 0.f;
        #pragma unroll
        for (int m=0;m<8;m++) acc += yv[m]*sW[m*8+k];
        u[k]=acc;
    }
    #pragma unroll
    for (int k=0;k<8;k++) zo[k] = tanhf(u[k]);
    #pragma unroll
    for (int i=0;i<8;i++){
        float tv = 0.f;
        #pragma unroll
        for (int k=0;k<8;k++) tv += zo[k]*sV[k*8+i];
        Fo[i] = (yv[i]-y0v[i])/dt - ((tv - 0.1f*yv[i]) + c0);
    }
}

static __device__ __forceinline__ void devInit2(const float* y0v,
    float* yold, float* dy, float* sj,
    float& fold_o, float& slope_o, float& resn_o, float& f2_o,
    float dt, float c0, const float* sW, const float* sV,
    float& rn_red, float& rat_red)
{
    #pragma unroll
    for (int i=0;i<8;i++){ yold[i]=y0v[i]; dy[i]=0.f; }
    float Fv[8], z[8];
    computeFz(y0v, y0v, dt, c0, sW, sV, Fv, z);
    #pragma unroll
    for (int k=0;k<8;k++) sj[k] = 1.0f - z[k]*z[k];
    float fold = 0.f;
    #pragma unroll
    for (int i=0;i<8;i++) fold += Fv[i]*Fv[i];
    float rn0 = fabsf(Fv[0]);
    #pragma unroll
    for (int i=1;i<8;i++) rn0 = nanmax2(rn0, fabsf(Fv[i]));
    fold_o=fold; slope_o=0.f; resn_o=rn0; f2_o=fold;
    rn_red  = nanmax2(rn_red, rn0);
    rat_red = nanmax2(rat_red, safe_div(rn0, 100.0f*rn0));
}

// Newton direction from current point y_cur; rebases yold:=y_cur, writes dy/sj/fold/slope.
static __device__ __forceinline__ void devA2(const float* y_cur, const float* y0v,
    float* yold, float* dy, float* sj, float& fold_o, float& slope_o,
    float dt, float invdt, float c0, const float* sW, const float* sV,
    bool recompute, float& gml, bool& nf)
{
    float Fv[8], z[8];
    computeFz(y_cur, y0v, dt, c0, sW, sV, Fv, z);
    if (recompute){
        #pragma unroll
        for (int k=0;k<8;k++) sj[k] = 1.0f - z[k]*z[k];
    }
    float J[8][8];
    #pragma unroll
    for (int j=0;j<8;j++){
        float zj[8];
        #pragma unroll
        for (int k=0;k<8;k++) zj[k] = sW[j*8+k]*sj[k];
        #pragma unroll
        for (int i=0;i<8;i++){
            float acc = 0.f;
            #pragma unroll
            for (int k=0;k<8;k++) acc += zj[k]*sV[k*8+i];
            J[i][j] = (i==j) ? (invdt - (acc - 0.1f)) : (0.0f - acc);
        }
    }
    float fold = 0.f;
    #pragma unroll
    for (int i=0;i<8;i++) fold += Fv[i]*Fv[i];
    float gv[8];
    #pragma unroll
    for (int j=0;j<8;j++){
        float acc = 0.f;
        #pragma unroll
        for (int i=0;i<8;i++) acc += Fv[i]*J[i][j];
        gv[j]=acc;
    }
    float x[8];
    #pragma unroll
    for (int i=0;i<8;i++) x[i]=Fv[i];
    #pragma unroll
    for (int c=0;c<8;c++){
        float ip = 1.0f / J[c][c];
        #pragma unroll
        for (int r2=c+1;r2<8;r2++){
            float m = J[r2][c]*ip;
            #pragma unroll
            for (int jj=c+1;jj<8;jj++) J[r2][jj] -= m*J[c][jj];
            x[r2] -= m*x[c];
        }
    }
    float wv[8];
    #pragma unroll
    for (int c=7;c>=0;c--){
        float acc = x[c];
        #pragma unroll
        for (int jj=c+1;jj<8;jj++) acc -= J[c][jj]*wv[jj];
        wv[c] = acc / J[c][c];
    }
    #pragma unroll
    for (int i=0;i<8;i++){
        yold[i] = y_cur[i];      // eager rebase (safe: freeze/idempotence analysis)
        dy[i]   = -wv[i];
    }
    float slope = 0.f;
    #pragma unroll
    for (int j=0;j<8;j++) slope += gv[j]*dy[j];
    fold_o = fold; slope_o = slope;
    #pragma unroll
    for (int i=0;i<8;i++){
        float rr = fabsf(dy[i]) / nanmax2(fabsf(y_cur[i]), 1.0f);
        gml = nanmax2(gml, rr);
        nf = nf || !__builtin_isfinite(dy[i]);
    }
}

static __device__ __forceinline__ void devB2(const float* yold, const float* dy,
    const float* y0v, float foldv, float slopev, float resnv, float f2v,
    float dt, float c0, const float* sW, const float* sV, float lam, float lam2v,
    float& tfo_o, float& trn_o,
    bool& armijo, float& lq, bool& aNot0, bool& dN, bool& ble,
    float& mX, float& mZ, float& mW, bool& nanf, float& trnR, float& ratR)
{
    float yn[8];
    #pragma unroll
    for (int i=0;i<8;i++) yn[i] = yold[i] + dy[i]*lam;
    float Ft[8], z[8];
    computeFz(yn, y0v, dt, c0, sW, sV, Ft, z);
    float f_obj = 0.f;
    #pragma unroll
    for (int i=0;i<8;i++) f_obj += Ft[i]*Ft[i];
    float rn = fabsf(Ft[0]);
    #pragma unroll
    for (int i=1;i<8;i++) rn = nanmax2(rn, fabsf(Ft[i]));
    tfo_o = f_obj; trn_o = rn;    // pending commit scalars
    armijo = armijo || (f_obj > (foldv + (ALPHA_C*lam)*slopev));
    lq = nanmin2(lq, safe_div((-slopev)*0.5f, (f_obj - foldv) - slopev));
    float lam1v = lam;
    float Af = safe_div(1.0f, lam1v - lam2v);
    float i1 = safe_div(1.0f, lam1v*lam1v);
    float i2 = safe_div(1.0f, lam2v*lam2v);
    float Cc0 = (f_obj - foldv) - lam1v*slopev;
    float Cc1 = (f2v   - foldv) - lam2v*slopev;
    float av = Af*(i1*Cc0 - i2*Cc1);
    float bv = Af*((-(lam2v*i1))*Cc0 + (lam1v*i2)*Cc1);
    float disc = bv*bv - (3.0f*av)*slopev;
    float dm = __builtin_isnan(disc) ? disc : fmaxf(disc, 0.0f);
    float sq = sqrtf(dm);
    aNot0 = aNot0 || (av != 0.0f);
    dN    = dN    || (disc < 0.0f);
    ble   = ble   || (bv <= 0.0f);
    mX = nanmin2(mX, safe_div(-slopev, 2.0f*bv));
    mZ = nanmin2(mZ, safe_div(-bv + sq, 3.0f*av));
    mW = nanmin2(mW, safe_div(-slopev, bv + sq));
    nanf = nanf || !__builtin_isfinite(f_obj);
    trnR = nanmax2(trnR, rn);
    ratR = nanmax2(ratR, safe_div(rn, resnv));
}

// ---------------- scalar control chain ----------------
struct ScalarState {
    float lam, lam1, lam2, lam_min, maxrn, ratmax;
    int   niter, exitflag;
    bool  upd_prev, cont_prev;
};

static __device__ void advance(ScalarState& s, const unsigned* R, int j){
    const unsigned* r = R + (size_t)(2 + j*NSLOT)*RSTRIDE;
    unsigned v0 = ldslot(r + (size_t)0*RSTRIDE);
    unsigned v1 = ldslot(r + (size_t)1*RSTRIDE);
    unsigned v2 = ldslot(r + (size_t)2*RSTRIDE);
    unsigned v3 = ldslot(r + (size_t)3*RSTRIDE);
    unsigned v4 = ldslot(r + (size_t)4*RSTRIDE);
    unsigned v5 = ldslot(r + (size_t)5*RSTRIDE);
    unsigned v6 = ldslot(r + (size_t)6*RSTRIDE);
    unsigned v7 = ldslot(r + (size_t)7*RSTRIDE);
    unsigned v8 = ldslot(r + (size_t)8*RSTRIDE);
    bool active    = ((s.maxrn > TOLFUN_C) || (s.lam < 1.0f)) && (s.exitflag >= 0) && (s.niter <= 1000);
    bool is_newton = (s.lam == 1.0f);
    float lam_min_new = is_newton ? safe_div(1e-12f, funkey(v0)) : s.lam_min;
    bool brk = (s.lam < lam_min_new);
    bool bad = is_newton ? (v1 != 0u) : false;
    bool upd = active && !brk && !bad;
    int niter_new = active ? (is_newton ? s.niter + 1 : s.niter) : s.niter;
    int ef_new = s.exitflag;
    if (active && brk) ef_new = 2;
    else if (active && !brk && bad) ef_new = -1;
    bool cont = false;
    if (upd){
        float lam1c = s.lam;
        unsigned bm = v8;
        bool backtrack = (bm & 1u) != 0u;
        float lamq  = funkey(v2);
        bool allA0  = (bm & 2u) == 0u;
        bool anyDN  = (bm & 4u) != 0u;
        bool anyB0  = (bm & 8u) != 0u;
        float lam_tmp_min = allA0 ? funkey(v3)
                          : (anyDN ? (0.5f*lam1c)
                          : (anyB0 ? funkey(v4) : funkey(v5)));
        float lam_cubic = nanmin2(lam_tmp_min, 0.5f*lam1c);
        float lam_bt = (s.lam == 1.0f) ? lamq : lam_cubic;
        bool nanf = (bm & 16u) != 0u;
        float lam_new = backtrack ? lam_bt : (nanf ? 0.5f*lam1c : 1.0f);
        cont = (lam_new < 1.0f);
        float lam2_new = cont ? lam1c : s.lam2;
        if (cont) lam_new = nanmax2(lam_new, 0.1f*lam1c);
        float maxrn_new  = cont ? s.maxrn  : funkey(v6);
        float ratmax_new = cont ? s.ratmax : funkey(v7);
        s.lam = lam_new; s.lam1 = lam1c; s.lam2 = lam2_new;
        s.lam_min = lam_min_new; s.maxrn = maxrn_new; s.ratmax = ratmax_new;
    }
    s.niter = niter_new; s.exitflag = ef_new;
    s.upd_prev = upd; s.cont_prev = cont;
}

static __device__ ScalarState replayN(const unsigned* R, int n){
    ScalarState s;
    s.lam=1.0f; s.lam1=1.0f; s.lam2=0.5f; s.lam_min=0.0f;
    s.maxrn  = funkey(ldslot(&R[0]));
    s.ratmax = funkey(ldslot(&R[(size_t)1*RSTRIDE]));
    s.niter=0; s.exitflag=1; s.upd_prev=false; s.cont_prev=false;
    for (int j=0;j<n;++j) advance(s, R, j);
    return s;
}

// ================= cooperative fused kernel =================
// y is NOT stored per-sample: y == yold + dy*lamc (lamc uniform).
// sj lives in LDS (element-major, conflict-free); y0 re-read from global.
__global__ __launch_bounds__(CNTHR, 1) void kFused(
    const float* __restrict__ y0g, const float* __restrict__ Wm, const float* __restrict__ Vm,
    const float* __restrict__ dtp, const float* __restrict__ tp,
    float* __restrict__ ws, float* __restrict__ out)
{
    cg::grid_group gridg = cg::this_grid();
    __shared__ float sW[64], sV[64];
    __shared__ float sSJ[8*SLOTS];      // 32 KB: sj element-major
    __shared__ float redF[6][4];
    __shared__ unsigned redB[4];
    int t = threadIdx.x;
    if (t < 64) sW[t] = Wm[t];
    else if (t < 128) sV[t-64] = Vm[t-64];
    unsigned* R = (unsigned*)(ws + OFF_R);
    if (blockIdx.x == 0 && t < R_TOT){
        unsigned v;
        if (t < 2) v = KEY_MAX_IDENT;
        else {
            int off = (t - 2) % NSLOT;
            bool ismin = (off==2 || off==3 || off==4 || off==5);
            bool ismax = (off==0 || off==6 || off==7);
            v = ismin ? KEY_MIN_IDENT : (ismax ? KEY_MAX_IDENT : 0u);
        }
        stslot(&R[(size_t)t*RSTRIDE], v);
    }
    __syncthreads();
    gridg.sync();

    int gtid = blockIdx.x*CNTHR + t;
    float dt = *dtp, invdt = 1.0f/dt, c0 = 0.01f*sinf(*tp);

    // per-sample persistent register state (22 floats/sample)
    bool  valid[SPT];
    float yold[SPT][8], dyv[SPT][8];
    float foldv[SPT], slopev[SPT], resnv[SPT], f2v[SPT], tfov[SPT], trnv[SPT];
    float lamc = 0.0f;   // uniform: y = yold + dy*lamc

    float rn_red = -__builtin_inff(), rat_red = -__builtin_inff();
    #pragma unroll
    for (int q=0;q<SPT;q++){
        int sid = gtid + q*CNT;
        int slot = q*CNTHR + t;
        valid[q] = sid < BSZ;
        if (valid[q]){
            float y0v[8], sjl[8];
            ld8(y0g + (size_t)sid*8, y0v);
            devInit2(y0v, yold[q], dyv[q], sjl,
                     foldv[q], slopev[q], resnv[q], f2v[q],
                     dt, c0, sW, sV, rn_red, rat_red);
            #pragma unroll
            for (int i=0;i<8;i++) sSJ[i*SLOTS + slot] = sjl[i];
            tfov[q]=0.f; trnv[q]=0.f;
        } else {
            #pragma unroll
            for (int i=0;i<8;i++){ sSJ[i*SLOTS + slot]=0; yold[q][i]=0; dyv[q][i]=0; }
            foldv[q]=0; slopev[q]=0; resnv[q]=0; f2v[q]=0; tfov[q]=0; trnv[q]=0;
        }
    }
    #pragma unroll
    for (int o=32;o>=1;o>>=1){
        rn_red  = nanmax2(rn_red,  __shfl_xor(rn_red,  o, 64));
        rat_red = nanmax2(rat_red, __shfl_xor(rat_red, o, 64));
    }
    {
        int w = t >> 6;
        if ((t & 63) == 0){ redF[0][w] = rn_red; redF[1][w] = rat_red; }
        __syncthreads();
        if (t == 0){
            float a = redF[0][0];
            #pragma unroll
            for (int w2=1;w2<4;w2++) a = nanmax2(a, redF[0][w2]);
            atomicMax(&R[0], fkey_max(a));
        } else if (t == 1){
            float b = redF[1][0];
            #pragma unroll
            for (int w2=1;w2<4;w2++) b = nanmax2(b, redF[1][w2]);
            atomicMax(&R[(size_t)1*RSTRIDE], fkey_max(b));
        }
    }
    gridg.sync();

    ScalarState S;
    S.lam=1.0f; S.lam1=1.0f; S.lam2=0.5f; S.lam_min=0.0f;
    S.maxrn  = funkey(ldslot(&R[0]));
    S.ratmax = funkey(ldslot(&R[(size_t)1*RSTRIDE]));
    S.niter=0; S.exitflag=1; S.upd_prev=false; S.cont_prev=false;

    #pragma unroll 1
    for (int k=1; k<=NSTEPS; ++k){
        // ---- commit pending trial from step k-1 (gate now known) ----
        if (S.upd_prev){
            lamc = S.lam1;
            #pragma unroll
            for (int q=0;q<SPT;q++){
                if (!valid[q]) continue;
                if (S.cont_prev) f2v[q]  = tfov[q];
                else             resnv[q] = trnv[q];
            }
        }
        bool active    = ((S.maxrn > TOLFUN_C) || (S.lam < 1.0f)) && (S.exitflag >= 0) && (S.niter <= 1000);
        bool is_newton = (S.lam == 1.0f);
        unsigned* r = R + (size_t)(2 + (k-1)*NSLOT)*RSTRIDE;

        if (active && is_newton){
            bool recompute = (S.ratmax > 0.2f);
            float gml = -__builtin_inff(); bool nf = false;
            #pragma unroll
            for (int q=0;q<SPT;q++){
                if (!valid[q]) continue;
                int sid = gtid + q*CNT;
                int slot = q*CNTHR + t;
                float y_cur[8], y0v[8], sjl[8];
                ld8(y0g + (size_t)sid*8, y0v);
                #pragma unroll
                for (int i=0;i<8;i++){
                    y_cur[i] = yold[q][i] + dyv[q][i]*lamc;
                    sjl[i]   = sSJ[i*SLOTS + slot];
                }
                devA2(y_cur, y0v, yold[q], dyv[q], sjl, foldv[q], slopev[q],
                      dt, invdt, c0, sW, sV, recompute, gml, nf);
                if (recompute){
                    #pragma unroll
                    for (int i=0;i<8;i++) sSJ[i*SLOTS + slot] = sjl[i];
                }
            }
            lamc = 0.0f;   // yold rebased to current y
            #pragma unroll
            for (int o=32;o>=1;o>>=1) gml = nanmax2(gml, __shfl_xor(gml, o, 64));
            unsigned long long anym = __ballot(nf ? 1 : 0);
            int w = t >> 6;
            if ((t & 63) == 0){ redF[0][w] = gml; redB[w] = anym ? 1u : 0u; }
            __syncthreads();
            if (t == 0){
                float v = redF[0][0];
                #pragma unroll
                for (int w2=1;w2<4;w2++) v = nanmax2(v, redF[0][w2]);
                atomicMax(&r[0], fkey_max(v));
            } else if (t == 1){
                unsigned bm = redB[0]|redB[1]|redB[2]|redB[3];
                if (bm) atomicOr(&r[(size_t)1*RSTRIDE], 1u);
            }
            __syncthreads();  // protect redF/redB reuse by phase B
        }

        if (active){
            float lam = S.lam, lam2v = S.lam2;
            bool armijo=false, aNot0=false, dN=false, ble=false, nanf=false;
            float lq=__builtin_inff(), mX=__builtin_inff(), mZ=__builtin_inff(), mW=__builtin_inff();
            float trnR=-__builtin_inff(), ratR=-__builtin_inff();
            #pragma unroll
            for (int q=0;q<SPT;q++){
                if (!valid[q]) continue;
                int sid = gtid + q*CNT;
                float y0v[8];
                ld8(y0g + (size_t)sid*8, y0v);
                devB2(yold[q], dyv[q], y0v, foldv[q], slopev[q], resnv[q], f2v[q],
                      dt, c0, sW, sV, lam, lam2v, tfov[q], trnv[q],
                      armijo, lq, aNot0, dN, ble, mX, mZ, mW, nanf, trnR, ratR);
            }
            #pragma unroll
            for (int o=32;o>=1;o>>=1){
                lq   = nanmin2(lq,   __shfl_xor(lq,   o, 64));
                mX   = nanmin2(mX,   __shfl_xor(mX,   o, 64));
                mZ   = nanmin2(mZ,   __shfl_xor(mZ,   o, 64));
                mW   = nanmin2(mW,   __shfl_xor(mW,   o, 64));
                trnR = nanmax2(trnR, __shfl_xor(trnR, o, 64));
                ratR = nanmax2(ratR, __shfl_xor(ratR, o, 64));
            }
            unsigned long long bArm = __ballot(armijo ? 1 : 0);
            unsigned long long bA0  = __ballot(aNot0  ? 1 : 0);
            unsigned long long bDN  = __ballot(dN     ? 1 : 0);
            unsigned long long bB0  = __ballot(ble    ? 1 : 0);
            unsigned long long bNF  = __ballot(nanf   ? 1 : 0);
            int w = t >> 6;
            if ((t & 63) == 0){
                redF[0][w]=lq; redF[1][w]=mX; redF[2][w]=mZ; redF[3][w]=mW;
                redF[4][w]=trnR; redF[5][w]=ratR;
                redB[w] = (bArm?1u:0u) | (bA0?2u:0u) | (bDN?4u:0u) | (bB0?8u:0u) | (bNF?16u:0u);
            }
            __syncthreads();
            if (t < 6){
                float v = redF[t][0];
                bool ismin = (t < 4);
                #pragma unroll
                for (int w2=1;w2<4;w2++) v = ismin ? nanmin2(v, redF[t][w2]) : nanmax2(v, redF[t][w2]);
                unsigned* p = &r[(size_t)(t + 2)*RSTRIDE];
                if (ismin) atomicMin(p, fkey_min(v));
                else       atomicMax(p, fkey_max(v));
            } else if (t == 6){
                unsigned bm = redB[0]|redB[1]|redB[2]|redB[3];
                if (bm) atomicOr(&r[(size_t)8*RSTRIDE], bm);
            }
        }

        gridg.sync();           // also block-syncs: protects redF reuse next iter
        advance(S, R, k-1);
    }

    if (S.upd_prev) lamc = S.lam1;   // final commit (y only; f2/resn not output)
    #pragma unroll
    for (int q=0;q<SPT;q++){
        if (!valid[q]) continue;
        int sid = gtid + q*CNT;
        float yf[8], y0v[8];
        ld8(y0g + (size_t)sid*8, y0v);
        #pragma unroll
        for (int i=0;i<8;i++) yf[i] = yold[q][i] + dyv[q][i]*lamc;
        st8(out + (size_t)sid*8, yf);
        float Fv[8], z[8];
        computeFz(yf, y0v, dt, c0, sW, sV, Fv, z);
        st8(out + (size_t)BSZ*8 + (size_t)sid*8, Fv);
    }
    if (gtid == 0) out[(size_t)BSZ*16] = (float)S.exitflag;
}

// ================= fallback path (same math, ws-resident state) =================
__global__ void kPre(unsigned* __restrict__ R){
    int i = threadIdx.x;
    if (i >= R_TOT) return;
    unsigned v;
    if (i < 2) v = KEY_MAX_IDENT;
    else {
        int off = (i - 2) % NSLOT;
        bool ismin = (off==2 || off==3 || off==4 || off==5);
        bool ismax = (off==0 || off==6 || off==7);
        v = ismin ? KEY_MIN_IDENT : (ismax ? KEY_MAX_IDENT : 0u);
    }
    R[(size_t)i*RSTRIDE] = v;
}

__global__ __launch_bounds__(FNTHR) void fInit(
    const float* __restrict__ y0g, const float* __restrict__ Wm, const float* __restrict__ Vm,
    const float* __restrict__ dtp, const float* __restrict__ tp, float* __restrict__ ws)
{
    __shared__ float sW[64], sV[64];
    __shared__ float red[2][4];
    int t = threadIdx.x;
    if (t < 64) sW[t] = Wm[t];
    else if (t < 128) sV[t-64] = Vm[t-64];
    __syncthreads();
    unsigned* R = (unsigned*)(ws + OFF_R);
    int tid = blockIdx.x*FNTHR + t;
    bool valid = tid < BSZ;
    float dt = *dtp, c0 = 0.01f*sinf(*tp);
    float rn_red = -__builtin_inff(), rat_red = -__builtin_inff();
    if (valid){
        float y0v[8], yo[8], dv[8], sj[8], fold, slope, resn, f2;
        ld8(y0g + (size_t)tid*8, y0v);
        devInit2(y0v, yo, dv, sj, fold, slope, resn, f2, dt, c0, sW, sV, rn_red, rat_red);
        st8(ws+OFF_Y   +(size_t)tid*8, y0v);
        st8(ws+OFF_YOLD+(size_t)tid*8, yo);
        st8(ws+OFF_DY  +(size_t)tid*8, dv);
        st8(ws+OFF_SJ  +(size_t)tid*8, sj);
        ws[OFF_FOLD+tid]=fold; ws[OFF_SLOPE+tid]=slope;
        ws[OFF_RESN+tid]=resn; ws[OFF_F2+tid]=f2;
        ws[OFF_TFO+tid]=0.f;   ws[OFF_TRN+tid]=0.f;
    }
    #pragma unroll
    for (int o=32;o>=1;o>>=1){
        rn_red  = nanmax2(rn_red,  __shfl_xor(rn_red,  o, 64));
        rat_red = nanmax2(rat_red, __shfl_xor(rat_red, o, 64));
    }
    int w = t >> 6;
    if ((t & 63) == 0){ red[0][w]=rn_red; red[1][w]=rat_red; }
    __syncthreads();
    if (t == 0){
        float a = red[0][0];
        for (int w2=1;w2<4;w2++) a = nanmax2(a, red[0][w2]);
        atomicMax(&R[0], fkey_max(a));
    } else if (t == 1){
        float b = red[1][0];
        for (int w2=1;w2<4;w2++) b = nanmax2(b, red[1][w2]);
        atomicMax(&R[(size_t)1*RSTRIDE], fkey_max(b));
    }
}

__global__ __launch_bounds__(FNTHR) void fStep(
    const float* __restrict__ y0g, const float* __restrict__ Wm, const float* __restrict__ Vm,
    const float* __restrict__ dtp, const float* __restrict__ tp,
    float* __restrict__ ws, int step)
{
    __shared__ float sW[64], sV[64];
    __shared__ float redF[6][4];
    __shared__ unsigned redB[4];
    int t = threadIdx.x;
    if (t < 64) sW[t] = Wm[t];
    else if (t < 128) sV[t-64] = Vm[t-64];
    __syncthreads();
    unsigned* R = (unsigned*)(ws + OFF_R);
    ScalarState S = replayN(R, step-1);
    bool active    = ((S.maxrn > TOLFUN_C) || (S.lam < 1.0f)) && (S.exitflag >= 0) && (S.niter <= 1000);
    bool is_newton = (S.lam == 1.0f);
    if (!S.upd_prev && !active) return;   // uniform

    int tid = blockIdx.x*FNTHR + t;
    bool valid = tid < BSZ;
    float dt = *dtp, invdt = 1.0f/dt, c0 = 0.01f*sinf(*tp);
    unsigned* r = R + (size_t)(2 + (step-1)*NSLOT)*RSTRIDE;

    float y0v[8], yv[8], yo[8], dv[8], sj[8], fold=0, slope=0, resn=0, f2=0;
    if (valid){
        ld8(y0g + (size_t)tid*8, y0v);
        ld8(ws+OFF_Y   +(size_t)tid*8, yv);
        ld8(ws+OFF_YOLD+(size_t)tid*8, yo);
        ld8(ws+OFF_DY  +(size_t)tid*8, dv);
        ld8(ws+OFF_SJ  +(size_t)tid*8, sj);
        fold=ws[OFF_FOLD+tid]; slope=ws[OFF_SLOPE+tid];
        resn=ws[OFF_RESN+tid]; f2=ws[OFF_F2+tid];
        if (S.upd_prev){
            #pragma unroll
            for (int i=0;i<8;i++) yv[i] = yo[i] + dv[i]*S.lam1;
            st8(ws+OFF_Y+(size_t)tid*8, yv);
            if (S.cont_prev){ f2 = ws[OFF_TFO+tid];  ws[OFF_F2+tid]   = f2; }
            else            { resn = ws[OFF_TRN+tid]; ws[OFF_RESN+tid] = resn; }
        }
    }
    if (!active) return;  // uniform

    if (is_newton){
        bool recompute = (S.ratmax > 0.2f);
        float gml = -__builtin_inff(); bool nf = false;
        if (valid){
            devA2(yv, y0v, yo, dv, sj, fold, slope, dt, invdt, c0, sW, sV, recompute, gml, nf);
            st8(ws+OFF_YOLD+(size_t)tid*8, yo);
            st8(ws+OFF_DY  +(size_t)tid*8, dv);
            if (recompute) st8(ws+OFF_SJ+(size_t)tid*8, sj);
            ws[OFF_FOLD+tid]  = fold;
            ws[OFF_SLOPE+tid] = slope;
        }
        #pragma unroll
        for (int o=32;o>=1;o>>=1) gml = nanmax2(gml, __shfl_xor(gml, o, 64));
        unsigned long long anym = __ballot(nf ? 1 : 0);
        int w = t >> 6;
        if ((t & 63) == 0){ redF[0][w] = gml; redB[w] = anym ? 1u : 0u; }
        __syncthreads();
        if (t == 0){
            float v = redF[0][0];
            for (int w2=1;w2<4;w2++) v = nanmax2(v, redF[0][w2]);
            atomicMax(&r[0], fkey_max(v));
        } else if (t == 1){
            unsigned bm = redB[0]|redB[1]|redB[2]|redB[3];
            if (bm) atomicOr(&r[(size_t)1*RSTRIDE], 1u);
        }
        __syncthreads();
    }

    {
        float lam = S.lam, lam2v = S.lam2;
        bool armijo=false, aNot0=false, dN=false, ble=false, nanf=false;
        float lq=__builtin_inff(), mX=__builtin_inff(), mZ=__builtin_inff(), mW=__builtin_inff();
        float trnR=-__builtin_inff(), ratR=-__builtin_inff();
        if (valid){
            float tfo, trn;
            devB2(yo, dv, y0v, fold, slope, resn, f2, dt, c0, sW, sV, lam, lam2v,
                  tfo, trn, armijo, lq, aNot0, dN, ble, mX, mZ, mW, nanf, trnR, ratR);
            ws[OFF_TFO+tid] = tfo;
            ws[OFF_TRN+tid] = trn;
        }
        #pragma unroll
        for (int o=32;o>=1;o>>=1){
            lq   = nanmin2(lq,   __shfl_xor(lq,   o, 64));
            mX   = nanmin2(mX,   __shfl_xor(mX,   o, 64));
            mZ   = nanmin2(mZ,   __shfl_xor(mZ,   o, 64));
            mW   = nanmin2(mW,   __shfl_xor(mW,   o, 64));
            trnR = nanmax2(trnR, __shfl_xor(trnR, o, 64));
            ratR = nanmax2(ratR, __shfl_xor(ratR, o, 64));
        }
        unsigned long long bArm = __ballot(armijo ? 1 : 0);
        unsigned long long bA0  = __ballot(aNot0  ? 1 : 0);
        unsigned long long bDN  = __ballot(dN     ? 1 : 0);
        unsigned long long bB0  = __ballot(ble    ? 1 : 0);
        unsigned long long bNF  = __ballot(nanf   ? 1 : 0);
        int w = t >> 6;
        if ((t & 63) == 0){
            redF[0][w]=lq; redF[1][w]=mX; redF[2][w]=mZ; redF[3][w]=mW;
            redF[4][w]=trnR; redF[5][w]=ratR;
            redB[w] = (bArm?1u:0u) | (bA0?2u:0u) | (bDN?4u:0u) | (bB0?8u:0u) | (bNF?16u:0u);
        }
        __syncthreads();
        if (t < 6){
            float v = redF[t][0];
            bool ismin = (t < 4);
            for (int w2=1;w2<4;w2++) v = ismin ? nanmin2(v, redF[t][w2]) : nanmax2(v, redF[t][w2]);
            unsigned* p = &r[(size_t)(t + 2)*RSTRIDE];
            if (ismin) atomicMin(p, fkey_min(v));
            else       atomicMax(p, fkey_max(v));
        } else if (t == 6){
            unsigned bm = redB[0]|redB[1]|redB[2]|redB[3];
            if (bm) atomicOr(&r[(size_t)8*RSTRIDE], bm);
        }
    }
}

__global__ __launch_bounds__(FNTHR) void fOut(
    const float* __restrict__ y0g, const float* __restrict__ Wm, const float* __restrict__ Vm,
    const float* __restrict__ dtp, const float* __restrict__ tp,
    const float* __restrict__ ws, float* __restrict__ out)
{
    __shared__ float sW[64], sV[64];
    int t = threadIdx.x;
    if (t < 64) sW[t] = Wm[t];
    else if (t < 128) sV[t-64] = Vm[t-64];
    __syncthreads();
    const unsigned* R = (const unsigned*)(ws + OFF_R);
    ScalarState S = replayN(R, NSTEPS);
    int tid = blockIdx.x*FNTHR + t;
    float dt = *dtp, c0 = 0.01f*sinf(*tp);
    if (tid < BSZ){
        float y0v[8], yv[8];
        ld8(y0g + (size_t)tid*8, y0v);
        ld8(ws+OFF_Y+(size_t)tid*8, yv);
        if (S.upd_prev){
            float yo[8], dv[8];
            ld8(ws+OFF_YOLD+(size_t)tid*8, yo);
            ld8(ws+OFF_DY  +(size_t)tid*8, dv);
            #pragma unroll
            for (int i=0;i<8;i++) yv[i] = yo[i] + dv[i]*S.lam1;
        }
        st8(out + (size_t)tid*8, yv);
        float Fv[8], z[8];
        computeFz(yv, y0v, dt, c0, sW, sV, Fv, z);
        st8(out + (size_t)BSZ*8 + (size_t)tid*8, Fv);
    }
    if (blockIdx.x == 0 && t == 0) out[(size_t)BSZ*16] = (float)S.exitflag;
}

extern "C" void kernel_launch(void* const* d_in, const int* in_sizes, int n_in,
                              void* d_out, int out_size, void* d_ws, size_t ws_size,
                              hipStream_t stream)
{
    const float* y0g = (const float*)d_in[0];
    const float* dtp = (const float*)d_in[1];
    const float* tp  = (const float*)d_in[2];
    const float* Wm  = (const float*)d_in[3];
    const float* Vm  = (const float*)d_in[4];
    float* ws   = (float*)d_ws;
    float* outp = (float*)d_out;

    // Capture-safe occupancy pre-check: never issue a coop launch that would
    // fail (a failed launch inside graph capture can invalidate the capture).
    int occ = 0;
    hipError_t qrc = hipOccupancyMaxActiveBlocksPerMultiprocessor(
        &occ, (const void*)kFused, CNTHR, 0);
    bool try_coop = (qrc == hipSuccess && occ >= 1);   // 256 blocks need 1 block/CU

    hipError_t rc = hipErrorUnknown;
    if (try_coop){
        void* args[] = {(void*)&y0g, (void*)&Wm, (void*)&Vm, (void*)&dtp, (void*)&tp,
                        (void*)&ws, (void*)&outp};
        rc = hipLaunchCooperativeKernel((const void*)kFused, dim3(CNBLK), dim3(CNTHR),
                                        args, 0, stream);
    }
    if (rc != hipSuccess){
        // deterministic fallback: same math, ws-resident state, 13 launches
        hipLaunchKernelGGL(kPre, dim3(1), dim3(128), 0, stream, (unsigned*)(ws + OFF_R));
        hipLaunchKernelGGL(fInit, dim3(FNBLK), dim3(FNTHR), 0, stream, y0g, Wm, Vm, dtp, tp, ws);
        for (int s = 1; s <= NSTEPS; ++s)
            hipLaunchKernelGGL(fStep, dim3(FNBLK), dim3(FNTHR), 0, stream, y0g, Wm, Vm, dtp, tp, ws, s);
        hipLaunchKernelGGL(fOut, dim3(FNBLK), dim3(FNTHR), 0, stream, y0g, Wm, Vm, dtp, tp, ws, outp);
    }
}

// Round 10
// 444.453 us; speedup vs baseline: 1.3057x; 1.0054x over previous
//
#include <hip/hip_runtime.h>
#include <hip/hip_cooperative_groups.h>

namespace cg = cooperative_groups;

#define BSZ 200000
#define NSTEPS 10
#define TOLFUN_C 1e-6f
#define ALPHA_C 1e-4f

// cooperative config: 512 blocks x 256 threads (2 blocks/CU at VGPR<=256),
// SPT=2. Persistent: yold,dy,F + 6 scalars = 30 floats/sample; sj + pending
// trial-F in LDS; y0 re-read from global only where needed (init/B/out).
#define CNTHR 256
#define CNBLK 512
#define CNT   (CNBLK*CNTHR)   /* 131072 threads */
#define SPT   2
#define SLOTS (CNTHR*SPT)     /* 512 per block */

// fallback config
#define FNTHR 256
#define FNBLK ((BSZ + FNTHR - 1)/FNTHR)

// ---------------- ws layout (float elements) ----------------
// State arrays used ONLY by the fallback path.
#define OFF_Y     ((size_t)0)
#define OFF_YOLD  ((size_t)BSZ*8)
#define OFF_DY    ((size_t)BSZ*16)
#define OFF_SJ    ((size_t)BSZ*24)
#define OFF_FOLD  ((size_t)BSZ*32)
#define OFF_SLOPE ((size_t)BSZ*33)
#define OFF_RESN  ((size_t)BSZ*34)
#define OFF_F2    ((size_t)BSZ*35)
#define OFF_TFO   ((size_t)BSZ*36)
#define OFF_TRN   ((size_t)BSZ*37)
#define OFF_R     ((size_t)BSZ*38)

// Reduction slots, each on its own 256B line.
#define RSTRIDE 64            /* uint words = 256 B */
#define NSLOT   9
#define R_TOT   (2 + NSTEPS*NSLOT)
// global: slot0 = max(rn0) key, slot1 = max(ratio0) key
// per step j, base (2+j*9)*RSTRIDE:
//  +0 maxGml(maxkey) +1 anyNFdy(bit) +2 minQuad(minkey) +3 minX(minkey)
//  +4 minZ(minkey) +5 minW(minkey) +6 maxTRN(maxkey) +7 maxRatio(maxkey)
//  +8 boolmask: b0 anyArmijo, b1 anyAnot0, b2 anyDiscNeg, b3 anyBle0, b4 anyNanF
#define KEY_MAX_IDENT 0x007FFFFFu  /* fkey(-inf) */
#define KEY_MIN_IDENT 0xFF800000u  /* fkey(+inf) */

static __device__ __forceinline__ float nanmax2(float a, float b){
    return (__builtin_isnan(a) || __builtin_isnan(b)) ? __builtin_nanf("") : fmaxf(a, b);
}
static __device__ __forceinline__ float nanmin2(float a, float b){
    return (__builtin_isnan(a) || __builtin_isnan(b)) ? __builtin_nanf("") : fminf(a, b);
}
static __device__ __forceinline__ float safe_div(float n, float d){
    return (fabsf(d) > 1e-30f) ? (n / d) : 0.0f;
}
static __device__ __forceinline__ unsigned fkey(float x){
    unsigned u = __float_as_uint(x);
    return (u & 0x80000000u) ? ~u : (u | 0x80000000u);
}
static __device__ __forceinline__ float funkey(unsigned u){
    return (u & 0x80000000u) ? __uint_as_float(u & 0x7FFFFFFFu) : __uint_as_float(~u);
}
static __device__ __forceinline__ unsigned fkey_max(float x){
    if (__builtin_isnan(x)) x = __uint_as_float(0x7FC00000u);
    return fkey(x);
}
static __device__ __forceinline__ unsigned fkey_min(float x){
    if (__builtin_isnan(x)) x = __uint_as_float(0xFFC00000u);
    return fkey(x);
}
static __device__ __forceinline__ void ld8(const float* p, float* v){
    float4 a = ((const float4*)p)[0], b = ((const float4*)p)[1];
    v[0]=a.x; v[1]=a.y; v[2]=a.z; v[3]=a.w; v[4]=b.x; v[5]=b.y; v[6]=b.z; v[7]=b.w;
}
static __device__ __forceinline__ void st8(float* p, const float* v){
    float4 a, b;
    a.x=v[0]; a.y=v[1]; a.z=v[2]; a.w=v[3];
    b.x=v[4]; b.y=v[5]; b.z=v[6]; b.w=v[7];
    ((float4*)p)[0]=a; ((float4*)p)[1]=b;
}
static __device__ __forceinline__ unsigned ldslot(const unsigned* p){
    return __hip_atomic_load(p, __ATOMIC_RELAXED, __HIP_MEMORY_SCOPE_AGENT);
}
static __device__ __forceinline__ void stslot(unsigned* p, unsigned v){
    __hip_atomic_store(p, v, __ATOMIC_RELAXED, __HIP_MEMORY_SCOPE_AGENT);
}

// ---------------- shared math (pointer-based; used by BOTH paths) ----------------
static __device__ __forceinline__ void computeFz(
    const float* yv, const float* y0v, float dt, float c0,
    const float* sW, const float* sV, float* Fo, float* zo)
{
    float u[8];
    #pragma unroll
    for (int k=0;k<8;k++){
        float acc = 0.f;
        #pragma unroll
        for (int m=0;m<8;m++) acc += yv[m]*sW[m*8+k];
        u[k]=acc;
    }
    #pragma unroll
    for (int k=0;k<8;k++) zo[k] = tanhf(u[k]);
    #pragma unroll
    for (int i=0;i<8;i++){
        float tv = 0.f;
        #pragma unroll
        for (int k=0;k<8;k++) tv += zo[k]*sV[k*8+i];
        Fo[i] = (yv[i]-y0v[i])/dt - ((tv - 0.1f*yv[i]) + c0);
    }
}

static __device__ __forceinline__ void devInit2(const float* y0v,
    float* yold, float* dy, float* sj, float* F_out,
    float& fold_o, float& slope_o, float& resn_o, float& f2_o,
    float dt, float c0, const float* sW, const float* sV,
    float& rn_red, float& rat_red)
{
    #pragma unroll
    for (int i=0;i<8;i++){ yold[i]=y0v[i]; dy[i]=0.f; }
    float z[8];
    computeFz(y0v, y0v, dt, c0, sW, sV, F_out, z);
    #pragma unroll
    for (int k=0;k<8;k++) sj[k] = 1.0f - z[k]*z[k];
    float fold = 0.f;
    #pragma unroll
    for (int i=0;i<8;i++) fold += F_out[i]*F_out[i];
    float rn0 = fabsf(F_out[0]);
    #pragma unroll
    for (int i=1;i<8;i++) rn0 = nanmax2(rn0, fabsf(F_out[i]));
    fold_o=fold; slope_o=0.f; resn_o=rn0; f2_o=fold;
    rn_red  = nanmax2(rn_red, rn0);
    rat_red = nanmax2(rat_red, safe_div(rn0, 100.0f*rn0));
}

// Fused-path Newton direction using carried F (no residual recompute).
// J depends only on sj/W/V/invdt; tanh recomputed only under `recompute`.
static __device__ __forceinline__ void devA3(const float* y_cur, const float* Fv,
    float* yold, float* dy, float* sj, float& fold_o, float& slope_o,
    float invdt, const float* sW, const float* sV,
    bool recompute, float& gml, bool& nf)
{
    if (recompute){
        float u[8];
        #pragma unroll
        for (int k=0;k<8;k++){
            float acc = 0.f;
            #pragma unroll
            for (int m=0;m<8;m++) acc += y_cur[m]*sW[m*8+k];
            u[k]=acc;
        }
        #pragma unroll
        for (int k=0;k<8;k++){ float z = tanhf(u[k]); sj[k] = 1.0f - z*z; }
    }
    float J[8][8];
    #pragma unroll
    for (int j=0;j<8;j++){
        float zj[8];
        #pragma unroll
        for (int k=0;k<8;k++) zj[k] = sW[j*8+k]*sj[k];
        #pragma unroll
        for (int i=0;i<8;i++){
            float acc = 0.f;
            #pragma unroll
            for (int k=0;k<8;k++) acc += zj[k]*sV[k*8+i];
            J[i][j] = (i==j) ? (invdt - (acc - 0.1f)) : (0.0f - acc);
        }
    }
    float fold = 0.f;
    #pragma unroll
    for (int i=0;i<8;i++) fold += Fv[i]*Fv[i];
    float gv[8];
    #pragma unroll
    for (int j=0;j<8;j++){
        float acc = 0.f;
        #pragma unroll
        for (int i=0;i<8;i++) acc += Fv[i]*J[i][j];
        gv[j]=acc;
    }
    float x[8];
    #pragma unroll
    for (int i=0;i<8;i++) x[i]=Fv[i];
    #pragma unroll
    for (int c=0;c<8;c++){
        float ip = 1.0f / J[c][c];
        #pragma unroll
        for (int r2=c+1;r2<8;r2++){
            float m = J[r2][c]*ip;
            #pragma unroll
            for (int jj=c+1;jj<8;jj++) J[r2][jj] -= m*J[c][jj];
            x[r2] -= m*x[c];
        }
    }
    float wv[8];
    #pragma unroll
    for (int c=7;c>=0;c--){
        float acc = x[c];
        #pragma unroll
        for (int jj=c+1;jj<8;jj++) acc -= J[c][jj]*wv[jj];
        wv[c] = acc / J[c][c];
    }
    #pragma unroll
    for (int i=0;i<8;i++){
        yold[i] = y_cur[i];      // eager rebase (safe: freeze/idempotence analysis)
        dy[i]   = -wv[i];
    }
    float slope = 0.f;
    #pragma unroll
    for (int j=0;j<8;j++) slope += gv[j]*dy[j];
    fold_o = fold; slope_o = slope;
    #pragma unroll
    for (int i=0;i<8;i++){
        float rr = fabsf(dy[i]) / nanmax2(fabsf(y_cur[i]), 1.0f);
        gml = nanmax2(gml, rr);
        nf = nf || !__builtin_isfinite(dy[i]);
    }
}

// Fallback-path Newton direction (recomputes residual; round-9 proven).
static __device__ __forceinline__ void devA2(const float* y_cur, const float* y0v,
    float* yold, float* dy, float* sj, float& fold_o, float& slope_o,
    float dt, float invdt, float c0, const float* sW, const float* sV,
    bool recompute, float& gml, bool& nf)
{
    float Fv[8], z[8];
    computeFz(y_cur, y0v, dt, c0, sW, sV, Fv, z);
    if (recompute){
        #pragma unroll
        for (int k=0;k<8;k++) sj[k] = 1.0f - z[k]*z[k];
    }
    // shared tail
    devA3(y_cur, Fv, yold, dy, sj, fold_o, slope_o, invdt, sW, sV, false, gml, nf);
}

static __device__ __forceinline__ void devB2(const float* yold, const float* dy,
    const float* y0v, float foldv, float slopev, float resnv, float f2v,
    float dt, float c0, const float* sW, const float* sV, float lam, float lam2v,
    float* Ft, float& tfo_o, float& trn_o,
    bool& armijo, float& lq, bool& aNot0, bool& dN, bool& ble,
    float& mX, float& mZ, float& mW, bool& nanf, float& trnR, float& ratR)
{
    float yn[8];
    #pragma unroll
    for (int i=0;i<8;i++) yn[i] = yold[i] + dy[i]*lam;
    float z[8];
    computeFz(yn, y0v, dt, c0, sW, sV, Ft, z);
    float f_obj = 0.f;
    #pragma unroll
    for (int i=0;i<8;i++) f_obj += Ft[i]*Ft[i];
    float rn = fabsf(Ft[0]);
    #pragma unroll
    for (int i=1;i<8;i++) rn = nanmax2(rn, fabsf(Ft[i]));
    tfo_o = f_obj; trn_o = rn;    // pending commit scalars
    armijo = armijo || (f_obj > (foldv + (ALPHA_C*lam)*slopev));
    lq = nanmin2(lq, safe_div((-slopev)*0.5f, (f_obj - foldv) - slopev));
    float lam1v = lam;
    float Af = safe_div(1.0f, lam1v - lam2v);
    float i1 = safe_div(1.0f, lam1v*lam1v);
    float i2 = safe_div(1.0f, lam2v*lam2v);
    float Cc0 = (f_obj - foldv) - lam1v*slopev;
    float Cc1 = (f2v   - foldv) - lam2v*slopev;
    float av = Af*(i1*Cc0 - i2*Cc1);
    float bv = Af*((-(lam2v*i1))*Cc0 + (lam1v*i2)*Cc1);
    float disc = bv*bv - (3.0f*av)*slopev;
    float dm = __builtin_isnan(disc) ? disc : fmaxf(disc, 0.0f);
    float sq = sqrtf(dm);
    aNot0 = aNot0 || (av != 0.0f);
    dN    = dN    || (disc < 0.0f);
    ble   = ble   || (bv <= 0.0f);
    mX = nanmin2(mX, safe_div(-slopev, 2.0f*bv));
    mZ = nanmin2(mZ, safe_div(-bv + sq, 3.0f*av));
    mW = nanmin2(mW, safe_div(-slopev, bv + sq));
    nanf = nanf || !__builtin_isfinite(f_obj);
    trnR = nanmax2(trnR, rn);
    ratR = nanmax2(ratR, safe_div(rn, resnv));
}

// ---------------- scalar control chain ----------------
struct ScalarState {
    float lam, lam1, lam2, lam_min, maxrn, ratmax;
    int   niter, exitflag;
    bool  upd_prev, cont_prev;
};

static __device__ void advance(ScalarState& s, const unsigned* R, int j){
    const unsigned* r = R + (size_t)(2 + j*NSLOT)*RSTRIDE;
    unsigned v0 = ldslot(r + (size_t)0*RSTRIDE);
    unsigned v1 = ldslot(r + (size_t)1*RSTRIDE);
    unsigned v2 = ldslot(r + (size_t)2*RSTRIDE);
    unsigned v3 = ldslot(r + (size_t)3*RSTRIDE);
    unsigned v4 = ldslot(r + (size_t)4*RSTRIDE);
    unsigned v5 = ldslot(r + (size_t)5*RSTRIDE);
    unsigned v6 = ldslot(r + (size_t)6*RSTRIDE);
    unsigned v7 = ldslot(r + (size_t)7*RSTRIDE);
    unsigned v8 = ldslot(r + (size_t)8*RSTRIDE);
    bool active    = ((s.maxrn > TOLFUN_C) || (s.lam < 1.0f)) && (s.exitflag >= 0) && (s.niter <= 1000);
    bool is_newton = (s.lam == 1.0f);
    float lam_min_new = is_newton ? safe_div(1e-12f, funkey(v0)) : s.lam_min;
    bool brk = (s.lam < lam_min_new);
    bool bad = is_newton ? (v1 != 0u) : false;
    bool upd = active && !brk && !bad;
    int niter_new = active ? (is_newton ? s.niter + 1 : s.niter) : s.niter;
    int ef_new = s.exitflag;
    if (active && brk) ef_new = 2;
    else if (active && !brk && bad) ef_new = -1;
    bool cont = false;
    if (upd){
        float lam1c = s.lam;
        unsigned bm = v8;
        bool backtrack = (bm & 1u) != 0u;
        float lamq  = funkey(v2);
        bool allA0  = (bm & 2u) == 0u;
        bool anyDN  = (bm & 4u) != 0u;
        bool anyB0  = (bm & 8u) != 0u;
        float lam_tmp_min = allA0 ? funkey(v3)
                          : (anyDN ? (0.5f*lam1c)
                          : (anyB0 ? funkey(v4) : funkey(v5)));
        float lam_cubic = nanmin2(lam_tmp_min, 0.5f*lam1c);
        float lam_bt = (s.lam == 1.0f) ? lamq : lam_cubic;
        bool nanf = (bm & 16u) != 0u;
        float lam_new = backtrack ? lam_bt : (nanf ? 0.5f*lam1c : 1.0f);
        cont = (lam_new < 1.0f);
        float lam2_new = cont ? lam1c : s.lam2;
        if (cont) lam_new = nanmax2(lam_new, 0.1f*lam1c);
        float maxrn_new  = cont ? s.maxrn  : funkey(v6);
        float ratmax_new = cont ? s.ratmax : funkey(v7);
        s.lam = lam_new; s.lam1 = lam1c; s.lam2 = lam2_new;
        s.lam_min = lam_min_new; s.maxrn = maxrn_new; s.ratmax = ratmax_new;
    }
    s.niter = niter_new; s.exitflag = ef_new;
    s.upd_prev = upd; s.cont_prev = cont;
}

static __device__ ScalarState replayN(const unsigned* R, int n){
    ScalarState s;
    s.lam=1.0f; s.lam1=1.0f; s.lam2=0.5f; s.lam_min=0.0f;
    s.maxrn  = funkey(ldslot(&R[0]));
    s.ratmax = funkey(ldslot(&R[(size_t)1*RSTRIDE]));
    s.niter=0; s.exitflag=1; s.upd_prev=false; s.cont_prev=false;
    for (int j=0;j<n;++j) advance(s, R, j);
    return s;
}

// ================= cooperative fused kernel =================
// y == yold + dy*lamc (lamc uniform). F carried in registers; pending trial-F
// staged in LDS and committed at the next step head once upd is known.
// sj in LDS (element-major, conflict-free).
__global__ __launch_bounds__(CNTHR, 2) void kFused(
    const float* __restrict__ y0g, const float* __restrict__ Wm, const float* __restrict__ Vm,
    const float* __restrict__ dtp, const float* __restrict__ tp,
    float* __restrict__ ws, float* __restrict__ out)
{
    cg::grid_group gridg = cg::this_grid();
    __shared__ float sW[64], sV[64];
    __shared__ float sSJ[8*SLOTS];      // 16 KB: sj element-major
    __shared__ float sFT[8*SLOTS];      // 16 KB: pending trial-F element-major
    __shared__ float redF[6][4];
    __shared__ unsigned redB[4];
    int t = threadIdx.x;
    if (t < 64) sW[t] = Wm[t];
    else if (t < 128) sV[t-64] = Vm[t-64];
    unsigned* R = (unsigned*)(ws + OFF_R);
    if (blockIdx.x == 0 && t < R_TOT){
        unsigned v;
        if (t < 2) v = KEY_MAX_IDENT;
        else {
            int off = (t - 2) % NSLOT;
            bool ismin = (off==2 || off==3 || off==4 || off==5);
            bool ismax = (off==0 || off==6 || off==7);
            v = ismin ? KEY_MIN_IDENT : (ismax ? KEY_MAX_IDENT : 0u);
        }
        stslot(&R[(size_t)t*RSTRIDE], v);
    }
    __syncthreads();
    gridg.sync();

    int gtid = blockIdx.x*CNTHR + t;
    float dt = *dtp, invdt = 1.0f/dt, c0 = 0.01f*sinf(*tp);

    // per-sample persistent register state (30 floats/sample)
    bool  valid[SPT];
    float yold[SPT][8], dyv[SPT][8], Fp[SPT][8];
    float foldv[SPT], slopev[SPT], resnv[SPT], f2v[SPT], tfov[SPT], trnv[SPT];
    float lamc = 0.0f;   // uniform: y = yold + dy*lamc

    float rn_red = -__builtin_inff(), rat_red = -__builtin_inff();
    #pragma unroll
    for (int q=0;q<SPT;q++){
        int sid = gtid + q*CNT;
        int slot = q*CNTHR + t;
        valid[q] = sid < BSZ;
        if (valid[q]){
            float y0v[8], sjl[8];
            ld8(y0g + (size_t)sid*8, y0v);
            devInit2(y0v, yold[q], dyv[q], sjl, Fp[q],
                     foldv[q], slopev[q], resnv[q], f2v[q],
                     dt, c0, sW, sV, rn_red, rat_red);
            #pragma unroll
            for (int i=0;i<8;i++) sSJ[i*SLOTS + slot] = sjl[i];
            tfov[q]=0.f; trnv[q]=0.f;
        } else {
            #pragma unroll
            for (int i=0;i<8;i++){ sSJ[i*SLOTS + slot]=0; yold[q][i]=0; dyv[q][i]=0; Fp[q][i]=0; }
            foldv[q]=0; slopev[q]=0; resnv[q]=0; f2v[q]=0; tfov[q]=0; trnv[q]=0;
        }
    }
    #pragma unroll
    for (int o=32;o>=1;o>>=1){
        rn_red  = nanmax2(rn_red,  __shfl_xor(rn_red,  o, 64));
        rat_red = nanmax2(rat_red, __shfl_xor(rat_red, o, 64));
    }
    {
        int w = t >> 6;
        if ((t & 63) == 0){ redF[0][w] = rn_red; redF[1][w] = rat_red; }
        __syncthreads();
        if (t == 0){
            float a = redF[0][0];
            #pragma unroll
            for (int w2=1;w2<4;w2++) a = nanmax2(a, redF[0][w2]);
            atomicMax(&R[0], fkey_max(a));
        } else if (t == 1){
            float b = redF[1][0];
            #pragma unroll
            for (int w2=1;w2<4;w2++) b = nanmax2(b, redF[1][w2]);
            atomicMax(&R[(size_t)1*RSTRIDE], fkey_max(b));
        }
    }
    gridg.sync();

    ScalarState S;
    S.lam=1.0f; S.lam1=1.0f; S.lam2=0.5f; S.lam_min=0.0f;
    S.maxrn  = funkey(ldslot(&R[0]));
    S.ratmax = funkey(ldslot(&R[(size_t)1*RSTRIDE]));
    S.niter=0; S.exitflag=1; S.upd_prev=false; S.cont_prev=false;

    #pragma unroll 1
    for (int k=1; k<=NSTEPS; ++k){
        // ---- commit pending trial from step k-1 (gate now known) ----
        if (S.upd_prev){
            lamc = S.lam1;
            #pragma unroll
            for (int q=0;q<SPT;q++){
                if (!valid[q]) continue;
                int slot = q*CNTHR + t;
                #pragma unroll
                for (int i=0;i<8;i++) Fp[q][i] = sFT[i*SLOTS + slot];
                if (S.cont_prev) f2v[q]  = tfov[q];
                else             resnv[q] = trnv[q];
            }
        }
        bool active    = ((S.maxrn > TOLFUN_C) || (S.lam < 1.0f)) && (S.exitflag >= 0) && (S.niter <= 1000);
        bool is_newton = (S.lam == 1.0f);
        unsigned* r = R + (size_t)(2 + (k-1)*NSLOT)*RSTRIDE;

        if (active && is_newton){
            bool recompute = (S.ratmax > 0.2f);
            float gml = -__builtin_inff(); bool nf = false;
            #pragma unroll
            for (int q=0;q<SPT;q++){
                if (!valid[q]) continue;
                int slot = q*CNTHR + t;
                float y_cur[8], sjl[8];
                #pragma unroll
                for (int i=0;i<8;i++){
                    y_cur[i] = yold[q][i] + dyv[q][i]*lamc;
                    sjl[i]   = sSJ[i*SLOTS + slot];
                }
                devA3(y_cur, Fp[q], yold[q], dyv[q], sjl, foldv[q], slopev[q],
                      invdt, sW, sV, recompute, gml, nf);
                if (recompute){
                    #pragma unroll
                    for (int i=0;i<8;i++) sSJ[i*SLOTS + slot] = sjl[i];
                }
            }
            lamc = 0.0f;   // yold rebased to current y
            #pragma unroll
            for (int o=32;o>=1;o>>=1) gml = nanmax2(gml, __shfl_xor(gml, o, 64));
            unsigned long long anym = __ballot(nf ? 1 : 0);
            int w = t >> 6;
            if ((t & 63) == 0){ redF[0][w] = gml; redB[w] = anym ? 1u : 0u; }
            __syncthreads();
            if (t == 0){
                float v = redF[0][0];
                #pragma unroll
                for (int w2=1;w2<4;w2++) v = nanmax2(v, redF[0][w2]);
                atomicMax(&r[0], fkey_max(v));
            } else if (t == 1){
                unsigned bm = redB[0]|redB[1]|redB[2]|redB[3];
                if (bm) atomicOr(&r[(size_t)1*RSTRIDE], 1u);
            }
            __syncthreads();  // protect redF/redB reuse by phase B
        }

        if (active){
            float lam = S.lam, lam2v = S.lam2;
            bool armijo=false, aNot0=false, dN=false, ble=false, nanf=false;
            float lq=__builtin_inff(), mX=__builtin_inff(), mZ=__builtin_inff(), mW=__builtin_inff();
            float trnR=-__builtin_inff(), ratR=-__builtin_inff();
            #pragma unroll
            for (int q=0;q<SPT;q++){
                if (!valid[q]) continue;
                int sid = gtid + q*CNT;
                int slot = q*CNTHR + t;
                float y0v[8], Ftl[8];
                ld8(y0g + (size_t)sid*8, y0v);
                devB2(yold[q], dyv[q], y0v, foldv[q], slopev[q], resnv[q], f2v[q],
                      dt, c0, sW, sV, lam, lam2v, Ftl, tfov[q], trnv[q],
                      armijo, lq, aNot0, dN, ble, mX, mZ, mW, nanf, trnR, ratR);
                #pragma unroll
                for (int i=0;i<8;i++) sFT[i*SLOTS + slot] = Ftl[i];
            }
            #pragma unroll
            for (int o=32;o>=1;o>>=1){
                lq   = nanmin2(lq,   __shfl_xor(lq,   o, 64));
                mX   = nanmin2(mX,   __shfl_xor(mX,   o, 64));
                mZ   = nanmin2(mZ,   __shfl_xor(mZ,   o, 64));
                mW   = nanmin2(mW,   __shfl_xor(mW,   o, 64));
                trnR = nanmax2(trnR, __shfl_xor(trnR, o, 64));
                ratR = nanmax2(ratR, __shfl_xor(ratR, o, 64));
            }
            unsigned long long bArm = __ballot(armijo ? 1 : 0);
            unsigned long long bA0  = __ballot(aNot0  ? 1 : 0);
            unsigned long long bDN  = __ballot(dN     ? 1 : 0);
            unsigned long long bB0  = __ballot(ble    ? 1 : 0);
            unsigned long long bNF  = __ballot(nanf   ? 1 : 0);
            int w = t >> 6;
            if ((t & 63) == 0){
                redF[0][w]=lq; redF[1][w]=mX; redF[2][w]=mZ; redF[3][w]=mW;
                redF[4][w]=trnR; redF[5][w]=ratR;
                redB[w] = (bArm?1u:0u) | (bA0?2u:0u) | (bDN?4u:0u) | (bB0?8u:0u) | (bNF?16u:0u);
            }
            __syncthreads();
            if (t < 6){
                float v = redF[t][0];
                bool ismin = (t < 4);
                #pragma unroll
                for (int w2=1;w2<4;w2++) v = ismin ? nanmin2(v, redF[t][w2]) : nanmax2(v, redF[t][w2]);
                unsigned* p = &r[(size_t)(t + 2)*RSTRIDE];
                if (ismin) atomicMin(p, fkey_min(v));
                else       atomicMax(p, fkey_max(v));
            } else if (t == 6){
                unsigned bm = redB[0]|redB[1]|redB[2]|redB[3];
                if (bm) atomicOr(&r[(size_t)8*RSTRIDE], bm);
            }
        }

        gridg.sync();           // also block-syncs: protects redF/sFT reuse
        advance(S, R, k-1);
    }

    // ---- final commit + output (F carried — no recompute) ----
    if (S.upd_prev){
        lamc = S.lam1;
        #pragma unroll
        for (int q=0;q<SPT;q++){
            if (!valid[q]) continue;
            int slot = q*CNTHR + t;
            #pragma unroll
            for (int i=0;i<8;i++) Fp[q][i] = sFT[i*SLOTS + slot];
        }
    }
    #pragma unroll
    for (int q=0;q<SPT;q++){
        if (!valid[q]) continue;
        int sid = gtid + q*CNT;
        float yf[8];
        #pragma unroll
        for (int i=0;i<8;i++) yf[i] = yold[q][i] + dyv[q][i]*lamc;
        st8(out + (size_t)sid*8, yf);
        st8(out + (size_t)BSZ*8 + (size_t)sid*8, Fp[q]);
    }
    if (gtid == 0) out[(size_t)BSZ*16] = (float)S.exitflag;
}

// ================= fallback path (same math, ws-resident state) =================
__global__ void kPre(unsigned* __restrict__ R){
    int i = threadIdx.x;
    if (i >= R_TOT) return;
    unsigned v;
    if (i < 2) v = KEY_MAX_IDENT;
    else {
        int off = (i - 2) % NSLOT;
        bool ismin = (off==2 || off==3 || off==4 || off==5);
        bool ismax = (off==0 || off==6 || off==7);
        v = ismin ? KEY_MIN_IDENT : (ismax ? KEY_MAX_IDENT : 0u);
    }
    R[(size_t)i*RSTRIDE] = v;
}

__global__ __launch_bounds__(FNTHR) void fInit(
    const float* __restrict__ y0g, const float* __restrict__ Wm, const float* __restrict__ Vm,
    const float* __restrict__ dtp, const float* __restrict__ tp, float* __restrict__ ws)
{
    __shared__ float sW[64], sV[64];
    __shared__ float red[2][4];
    int t = threadIdx.x;
    if (t < 64) sW[t] = Wm[t];
    else if (t < 128) sV[t-64] = Vm[t-64];
    __syncthreads();
    unsigned* R = (unsigned*)(ws + OFF_R);
    int tid = blockIdx.x*FNTHR + t;
    bool valid = tid < BSZ;
    float dt = *dtp, c0 = 0.01f*sinf(*tp);
    float rn_red = -__builtin_inff(), rat_red = -__builtin_inff();
    if (valid){
        float y0v[8], yo[8], dv[8], sj[8], Fv[8], fold, slope, resn, f2;
        ld8(y0g + (size_t)tid*8, y0v);
        devInit2(y0v, yo, dv, sj, Fv, fold, slope, resn, f2, dt, c0, sW, sV, rn_red, rat_red);
        st8(ws+OFF_Y   +(size_t)tid*8, y0v);
        st8(ws+OFF_YOLD+(size_t)tid*8, yo);
        st8(ws+OFF_DY  +(size_t)tid*8, dv);
        st8(ws+OFF_SJ  +(size_t)tid*8, sj);
        ws[OFF_FOLD+tid]=fold; ws[OFF_SLOPE+tid]=slope;
        ws[OFF_RESN+tid]=resn; ws[OFF_F2+tid]=f2;
        ws[OFF_TFO+tid]=0.f;   ws[OFF_TRN+tid]=0.f;
    }
    #pragma unroll
    for (int o=32;o>=1;o>>=1){
        rn_red  = nanmax2(rn_red,  __shfl_xor(rn_red,  o, 64));
        rat_red = nanmax2(rat_red, __shfl_xor(rat_red, o, 64));
    }
    int w = t >> 6;
    if ((t & 63) == 0){ red[0][w]=rn_red; red[1][w]=rat_red; }
    __syncthreads();
    if (t == 0){
        float a = red[0][0];
        for (int w2=1;w2<4;w2++) a = nanmax2(a, red[0][w2]);
        atomicMax(&R[0], fkey_max(a));
    } else if (t == 1){
        float b = red[1][0];
        for (int w2=1;w2<4;w2++) b = nanmax2(b, red[1][w2]);
        atomicMax(&R[(size_t)1*RSTRIDE], fkey_max(b));
    }
}

__global__ __launch_bounds__(FNTHR) void fStep(
    const float* __restrict__ y0g, const float* __restrict__ Wm, const float* __restrict__ Vm,
    const float* __restrict__ dtp, const float* __restrict__ tp,
    float* __restrict__ ws, int step)
{
    __shared__ float sW[64], sV[64];
    __shared__ float redF[6][4];
    __shared__ unsigned redB[4];
    int t = threadIdx.x;
    if (t < 64) sW[t] = Wm[t];
    else if (t < 128) sV[t-64] = Vm[t-64];
    __syncthreads();
    unsigned* R = (unsigned*)(ws + OFF_R);
    ScalarState S = replayN(R, step-1);
    bool active    = ((S.maxrn > TOLFUN_C) || (S.lam < 1.0f)) && (S.exitflag >= 0) && (S.niter <= 1000);
    bool is_newton = (S.lam == 1.0f);
    if (!S.upd_prev && !active) return;   // uniform

    int tid = blockIdx.x*FNTHR + t;
    bool valid = tid < BSZ;
    float dt = *dtp, invdt = 1.0f/dt, c0 = 0.01f*sinf(*tp);
    unsigned* r = R + (size_t)(2 + (step-1)*NSLOT)*RSTRIDE;

    float y0v[8], yv[8], yo[8], dv[8], sj[8], fold=0, slope=0, resn=0, f2=0;
    if (valid){
        ld8(y0g + (size_t)tid*8, y0v);
        ld8(ws+OFF_Y   +(size_t)tid*8, yv);
        ld8(ws+OFF_YOLD+(size_t)tid*8, yo);
        ld8(ws+OFF_DY  +(size_t)tid*8, dv);
        ld8(ws+OFF_SJ  +(size_t)tid*8, sj);
        fold=ws[OFF_FOLD+tid]; slope=ws[OFF_SLOPE+tid];
        resn=ws[OFF_RESN+tid]; f2=ws[OFF_F2+tid];
        if (S.upd_prev){
            #pragma unroll
            for (int i=0;i<8;i++) yv[i] = yo[i] + dv[i]*S.lam1;
            st8(ws+OFF_Y+(size_t)tid*8, yv);
            if (S.cont_prev){ f2 = ws[OFF_TFO+tid];  ws[OFF_F2+tid]   = f2; }
            else            { resn = ws[OFF_TRN+tid]; ws[OFF_RESN+tid] = resn; }
        }
    }
    if (!active) return;  // uniform

    if (is_newton){
        bool recompute = (S.ratmax > 0.2f);
        float gml = -__builtin_inff(); bool nf = false;
        if (valid){
            devA2(yv, y0v, yo, dv, sj, fold, slope, dt, invdt, c0, sW, sV, recompute, gml, nf);
            st8(ws+OFF_YOLD+(size_t)tid*8, yo);
            st8(ws+OFF_DY  +(size_t)tid*8, dv);
            if (recompute) st8(ws+OFF_SJ+(size_t)tid*8, sj);
            ws[OFF_FOLD+tid]  = fold;
            ws[OFF_SLOPE+tid] = slope;
        }
        #pragma unroll
        for (int o=32;o>=1;o>>=1) gml = nanmax2(gml, __shfl_xor(gml, o, 64));
        unsigned long long anym = __ballot(nf ? 1 : 0);
        int w = t >> 6;
        if ((t & 63) == 0){ redF[0][w] = gml; redB[w] = anym ? 1u : 0u; }
        __syncthreads();
        if (t == 0){
            float v = redF[0][0];
            for (int w2=1;w2<4;w2++) v = nanmax2(v, redF[0][w2]);
            atomicMax(&r[0], fkey_max(v));
        } else if (t == 1){
            unsigned bm = redB[0]|redB[1]|redB[2]|redB[3];
            if (bm) atomicOr(&r[(size_t)1*RSTRIDE], 1u);
        }
        __syncthreads();
    }

    {
        float lam = S.lam, lam2v = S.lam2;
        bool armijo=false, aNot0=false, dN=false, ble=false, nanf=false;
        float lq=__builtin_inff(), mX=__builtin_inff(), mZ=__builtin_inff(), mW=__builtin_inff();
        float trnR=-__builtin_inff(), ratR=-__builtin_inff();
        if (valid){
            float tfo, trn, Ftl[8];
            devB2(yo, dv, y0v, fold, slope, resn, f2, dt, c0, sW, sV, lam, lam2v,
                  Ftl, tfo, trn, armijo, lq, aNot0, dN, ble, mX, mZ, mW, nanf, trnR, ratR);
            ws[OFF_TFO+tid] = tfo;
            ws[OFF_TRN+tid] = trn;
        }
        #pragma unroll
        for (int o=32;o>=1;o>>=1){
            lq   = nanmin2(lq,   __shfl_xor(lq,   o, 64));
            mX   = nanmin2(mX,   __shfl_xor(mX,   o, 64));
            mZ   = nanmin2(mZ,   __shfl_xor(mZ,   o, 64));
            mW   = nanmin2(mW,   __shfl_xor(mW,   o, 64));
            trnR = nanmax2(trnR, __shfl_xor(trnR, o, 64));
            ratR = nanmax2(ratR, __shfl_xor(ratR, o, 64));
        }
        unsigned long long bArm = __ballot(armijo ? 1 : 0);
        unsigned long long bA0  = __ballot(aNot0  ? 1 : 0);
        unsigned long long bDN  = __ballot(dN     ? 1 : 0);
        unsigned long long bB0  = __ballot(ble    ? 1 : 0);
        unsigned long long bNF  = __ballot(nanf   ? 1 : 0);
        int w = t >> 6;
        if ((t & 63) == 0){
            redF[0][w]=lq; redF[1][w]=mX; redF[2][w]=mZ; redF[3][w]=mW;
            redF[4][w]=trnR; redF[5][w]=ratR;
            redB[w] = (bArm?1u:0u) | (bA0?2u:0u) | (bDN?4u:0u) | (bB0?8u:0u) | (bNF?16u:0u);
        }
        __syncthreads();
        if (t < 6){
            float v = redF[t][0];
            bool ismin = (t < 4);
            for (int w2=1;w2<4;w2++) v = ismin ? nanmin2(v, redF[t][w2]) : nanmax2(v, redF[t][w2]);
            unsigned* p = &r[(size_t)(t + 2)*RSTRIDE];
            if (ismin) atomicMin(p, fkey_min(v));
            else       atomicMax(p, fkey_max(v));
        } else if (t == 6){
            unsigned bm = redB[0]|redB[1]|redB[2]|redB[3];
            if (bm) atomicOr(&r[(size_t)8*RSTRIDE], bm);
        }
    }
}

__global__ __launch_bounds__(FNTHR) void fOut(
    const float* __restrict__ y0g, const float* __restrict__ Wm, const float* __restrict__ Vm,
    const float* __restrict__ dtp, const float* __restrict__ tp,
    const float* __restrict__ ws, float* __restrict__ out)
{
    __shared__ float sW[64], sV[64];
    int t = threadIdx.x;
    if (t < 64) sW[t] = Wm[t];
    else if (t < 128) sV[t-64] = Vm[t-64];
    __syncthreads();
    const unsigned* R = (const unsigned*)(ws + OFF_R);
    ScalarState S = replayN(R, NSTEPS);
    int tid = blockIdx.x*FNTHR + t;
    float dt = *dtp, c0 = 0.01f*sinf(*tp);
    if (tid < BSZ){
        float y0v[8], yv[8];
        ld8(y0g + (size_t)tid*8, y0v);
        ld8(ws+OFF_Y+(size_t)tid*8, yv);
        if (S.upd_prev){
            float yo[8], dv[8];
            ld8(ws+OFF_YOLD+(size_t)tid*8, yo);
            ld8(ws+OFF_DY  +(size_t)tid*8, dv);
            #pragma unroll
            for (int i=0;i<8;i++) yv[i] = yo[i] + dv[i]*S.lam1;
        }
        st8(out + (size_t)tid*8, yv);
        float Fv[8], z[8];
        computeFz(yv, y0v, dt, c0, sW, sV, Fv, z);
        st8(out + (size_t)BSZ*8 + (size_t)tid*8, Fv);
    }
    if (blockIdx.x == 0 && t == 0) out[(size_t)BSZ*16] = (float)S.exitflag;
}

extern "C" void kernel_launch(void* const* d_in, const int* in_sizes, int n_in,
                              void* d_out, int out_size, void* d_ws, size_t ws_size,
                              hipStream_t stream)
{
    const float* y0g = (const float*)d_in[0];
    const float* dtp = (const float*)d_in[1];
    const float* tp  = (const float*)d_in[2];
    const float* Wm  = (const float*)d_in[3];
    const float* Vm  = (const float*)d_in[4];
    float* ws   = (float*)d_ws;
    float* outp = (float*)d_out;

    // Capture-safe occupancy pre-check: never issue a coop launch that would
    // fail (a failed launch inside graph capture can invalidate the capture).
    int occ = 0;
    hipError_t qrc = hipOccupancyMaxActiveBlocksPerMultiprocessor(
        &occ, (const void*)kFused, CNTHR, 0);
    bool try_coop = (qrc == hipSuccess && occ * 256 >= CNBLK);  // need 2 blocks/CU

    hipError_t rc = hipErrorUnknown;
    if (try_coop){
        void* args[] = {(void*)&y0g, (void*)&Wm, (void*)&Vm, (void*)&dtp, (void*)&tp,
                        (void*)&ws, (void*)&outp};
        rc = hipLaunchCooperativeKernel((const void*)kFused, dim3(CNBLK), dim3(CNTHR),
                                        args, 0, stream);
    }
    if (rc != hipSuccess){
        // deterministic fallback: same math, ws-resident state, 13 launches
        hipLaunchKernelGGL(kPre, dim3(1), dim3(128), 0, stream, (unsigned*)(ws + OFF_R));
        hipLaunchKernelGGL(fInit, dim3(FNBLK), dim3(FNTHR), 0, stream, y0g, Wm, Vm, dtp, tp, ws);
        for (int s = 1; s <= NSTEPS; ++s)
            hipLaunchKernelGGL(fStep, dim3(FNBLK), dim3(FNTHR), 0, stream, y0g, Wm, Vm, dtp, tp, ws, s);
        hipLaunchKernelGGL(fOut, dim3(FNBLK), dim3(FNTHR), 0, stream, y0g, Wm, Vm, dtp, tp, ws, outp);
    }
}